// Round 6
// baseline (1827.900 us; speedup 1.0000x reference)
//
#include <hip/hip_runtime.h>
#include <hip/hip_bf16.h>

#define NN 50000
#define DD 512
#define KE 128
#define TJN 4
#define BNEPS 1e-5f
#define ZC 64       // split-K chunks
#define KPAD 50016  // NN padded to mult of 32 (zero-filled in transposed operands)
#define SKE 800     // K-elems per split-K chunk (25 steps of 32; 64*800 >= KPAD)

typedef __attribute__((ext_vector_type(8))) short short8;
typedef __attribute__((ext_vector_type(4))) float floatx4;

__device__ __forceinline__ float bf2f(unsigned short h){
  return __uint_as_float(((unsigned int)h) << 16);
}
__device__ __forceinline__ unsigned short f2bf(float f){
  unsigned int u = __float_as_uint(f);
  unsigned int r = (u + 0x7FFF + ((u >> 16) & 1)) >> 16;
  return (unsigned short)r;
}
__device__ __forceinline__ float load1(const void* p, long i, int bf){
  if (bf) return bf2f(((const unsigned short*)p)[i]);
  return ((const float*)p)[i];
}
__device__ __forceinline__ void store1(void* p, long i, int bf, float v){
  if (bf) ((unsigned short*)p)[i] = f2bf(v);
  else ((float*)p)[i] = v;
}

// async global->LDS 16B (dest = wave-uniform base + lane*16)
typedef __attribute__((address_space(3))) unsigned int lds_uint_t;
typedef __attribute__((address_space(1))) unsigned int gbl_uint_t;
__device__ __forceinline__ void gload16(const void* gp, void* lp){
  __builtin_amdgcn_global_load_lds((const gbl_uint_t*)gp, (lds_uint_t*)lp, 16, 0, 0);
}

// ---------------- dtype sniffing ----------------
__global__ void detect_kernel(const void* xraw, const void* eraw, int* flags){
  if (blockIdx.x == 0 && threadIdx.x == 0){
    const unsigned short* p = (const unsigned short*)xraw;
    int cnt = 0;
    for (int i = 0; i < 128; i++){
      int e = (p[i] >> 7) & 0xFF;
      if (e >= 110 && e <= 133) cnt++;
    }
    flags[0] = (cnt >= 96) ? 1 : 0;
    const unsigned int* q = (const unsigned int*)eraw;
    int z = 0;
    for (int i = 0; i < 64; i++) if (q[2*i+1] == 0u) z++;
    flags[1] = (z >= 48) ? 1 : 0;
  }
}

// all small parameter vectors in one launch; dst layout matches alloc order:
// [filt 512][bgcn 512][b2 512][bfus 512][bff1 1024][bff2 512][bn 6x512]
struct P13 { const void* p[12]; };
__global__ void cvt_params(P13 pp, float* __restrict__ dst, const int* __restrict__ flags){
  int bf = flags[0];
  int i = blockIdx.x * 256 + threadIdx.x;
  if (i >= 6656) return;
  const void* s; int off;
  if (i < 2048){ s = pp.p[i >> 9]; off = i & 511; }
  else if (i < 3072){ s = pp.p[4]; off = i - 2048; }
  else if (i < 3584){ s = pp.p[5]; off = i - 3072; }
  else { int j = (i - 3584) >> 9; s = pp.p[6 + j]; off = (i - 3584) & 511; }
  dst[i] = load1(s, off, bf);
}

// fused: read raw src[K][Nc] (dtype per flags), write straight bf16 dst1[K][Nc]
// AND transposed bf16 dst2[Nc][ldK] with zero-fill for cols in [K, ldK).
__global__ __launch_bounds__(256) void cvt_bt(
    const void* __restrict__ src, unsigned short* __restrict__ dst1,
    unsigned short* __restrict__ dst2, int K, int Nc, int ldK,
    const int* __restrict__ flags){
  int bf = flags[0];
  __shared__ unsigned short T[64][66];
  int bk = blockIdx.y * 64, bc = blockIdx.x * 64;
  int tid = threadIdx.x;
#pragma unroll
  for (int p = 0; p < 16; p++){
    int idx = p * 256 + tid;
    int r = idx >> 6, c = idx & 63;
    unsigned short h = 0;
    if (bk + r < K){
      h = f2bf(load1(src, (long)(bk + r) * Nc + bc + c, bf));
      dst1[(long)(bk + r) * Nc + bc + c] = h;
    }
    T[r][c] = h;
  }
  __syncthreads();
#pragma unroll
  for (int p = 0; p < 16; p++){
    int idx = p * 256 + tid;
    int r = idx >> 6, c = idx & 63;
    if (bk + c < ldK)
      dst2[(long)(bc + r) * ldK + bk + c] = T[c][r];
  }
}

// tiled transpose+cvt: dst[Nc][ldK] (bf16) = src[K][Nc]; zero-fills dst cols in [K, ldK).
__global__ __launch_bounds__(256) void cvt_t(
    const void* __restrict__ src, unsigned short* __restrict__ dst,
    int K, int Nc, int ldK, long srcz, long dstz, int smode,
    const int* __restrict__ flags){
  int bf = (smode == 2) ? flags[0] : smode;
  __shared__ unsigned short T[64][66];
  int bk = blockIdx.y * 64, bc = blockIdx.x * 64;
  long so = (long)blockIdx.z * srcz;
  long dof = (long)blockIdx.z * dstz;
  int tid = threadIdx.x;
#pragma unroll
  for (int p = 0; p < 16; p++){
    int idx = p * 256 + tid;
    int r = idx >> 6, c = idx & 63;
    float v = 0.f;
    if (bk + r < K) v = load1(src, so + (long)(bk + r) * Nc + bc + c, bf);
    T[r][c] = f2bf(v);
  }
  __syncthreads();
#pragma unroll
  for (int p = 0; p < 16; p++){
    int idx = p * 256 + tid;
    int r = idx >> 6, c = idx & 63;
    if (bk + c < ldK)
      dst[dof + (long)(bc + r) * ldK + bk + c] = T[c][r];
  }
}

__global__ void cvt_idx(const void* __restrict__ src, int* __restrict__ dst,
                        long n, const int* __restrict__ flags){
  int w64 = flags[1];
  long i = (long)blockIdx.x * blockDim.x + threadIdx.x;
  long stride = (long)gridDim.x * blockDim.x;
  for (; i < n; i += stride)
    dst[i] = w64 ? (int)((const long long*)src)[i] : ((const int*)src)[i];
}

// ---------------- CSR build ----------------
__global__ void deg_kernel(const int* __restrict__ dst, int* __restrict__ deg, int E){
  int i = blockIdx.x * blockDim.x + threadIdx.x;
  if (i < E) atomicAdd(&deg[dst[i]], 1);
}

__global__ __launch_bounds__(1024) void scan_kernel(const int* __restrict__ deg,
                                                    int* __restrict__ rowptr, int E){
  __shared__ int lds[1024];
  int t = threadIdx.x;
  const int CH = (NN + 1023) / 1024;   // 49
  int base = t * CH;
  int s = 0;
  for (int i = 0; i < CH; i++){
    int idx = base + i;
    if (idx < NN) s += deg[idx];
  }
  lds[t] = s;
  __syncthreads();
  for (int off = 1; off < 1024; off <<= 1){
    int v = (t >= off) ? lds[t - off] : 0;
    __syncthreads();
    lds[t] += v;
    __syncthreads();
  }
  int ex = (t == 0) ? 0 : lds[t - 1];
  for (int i = 0; i < CH; i++){
    int idx = base + i;
    if (idx < NN){ rowptr[idx] = ex; ex += deg[idx]; }
  }
  if (t == 1023) rowptr[NN] = ex;
}

__global__ void dinv_kernel(const int* __restrict__ deg, float* __restrict__ dinv){
  int i = blockIdx.x * blockDim.x + threadIdx.x;
  if (i < NN) dinv[i] = rsqrtf((float)deg[i] + 1.0f);
}

__global__ void scatter_kernel(const int* __restrict__ srcv, const int* __restrict__ dstv,
                               const int* __restrict__ rowptr, int* __restrict__ cursor,
                               int* __restrict__ csr, int E){
  int i = blockIdx.x * blockDim.x + threadIdx.x;
  if (i < E){
    int d = dstv[i];
    int pos = atomicAdd(&cursor[d], 1);
    csr[rowptr[d] + pos] = srcv[i];
  }
}

// ---------------- fused GCN gather (agg + self-loop + residual + bias) ----------------
__global__ __launch_bounds__(64) void gcn_gather(
    const int* __restrict__ rowptr, const int* __restrict__ csr,
    const float* __restrict__ dinv, const void* __restrict__ xw /*bf16*/,
    const void* __restrict__ X, const float* __restrict__ bias,
    float* __restrict__ out, const int* __restrict__ flags){
  int d = blockIdx.x;
  int lane = threadIdx.x;
  __shared__ int s_idx[64];
  __shared__ float s_dv[64];
  int start = rowptr[d], end = rowptr[d + 1];
  float dd = dinv[d];
  float acc[8];
#pragma unroll
  for (int k = 0; k < 8; k++) acc[k] = 0.f;
  const unsigned short* xwp = (const unsigned short*)xw;
  int c0 = lane * 8;
  for (int j0 = start; j0 < end; j0 += 64){
    int cnt = min(64, end - j0);
    __syncthreads();
    if (lane < cnt){
      int s = csr[j0 + lane];
      s_idx[lane] = s;
      s_dv[lane] = dinv[s];
    }
    __syncthreads();
    for (int t = 0; t < cnt; t++){
      int s = s_idx[t];
      float nm = dd * s_dv[t];
      union { float4 f; unsigned short u[8]; } r;
      r.f = *(const float4*)(xwp + (long)s * DD + c0);
#pragma unroll
      for (int k = 0; k < 8; k++) acc[k] += nm * bf2f(r.u[k]);
    }
  }
  int xf = flags[0];
  long base = (long)d * DD + c0;
  union { float4 f; unsigned short u[8]; } sf;
  sf.f = *(const float4*)(xwp + base);
  float d2 = dd * dd;
#pragma unroll
  for (int k = 0; k < 8; k++)
    out[base + k] = load1(X, base + k, xf) + acc[k] + d2 * bf2f(sf.u[k]) + bias[c0 + k];
}

// ---------------- batch norm ----------------
__global__ __launch_bounds__(512) void bn_stats(const float* __restrict__ T,
                                                float* __restrict__ sum,
                                                float* __restrict__ sumsq){
  int c = threadIdx.x;
  long r0 = (long)blockIdx.x * 128;
  float s = 0.f, q = 0.f;
  for (int r = 0; r < 128; r++){
    long rr = r0 + r;
    if (rr < NN){
      float v = T[rr * DD + c];
      s += v; q += v * v;
    }
  }
  atomicAdd(&sum[c], s);
  atomicAdd(&sumsq[c], q);
}

__global__ void bn_apply(const float* __restrict__ T,
                         const float* __restrict__ sum, const float* __restrict__ sumsq,
                         const float* __restrict__ g, const float* __restrict__ b,
                         const void* __restrict__ addsrc, int addmode,
                         void* __restrict__ out, int outmode,
                         unsigned short* __restrict__ out2,
                         const int* __restrict__ flags){
  int am = (addmode == 2) ? flags[0] : addmode;
  int om = (outmode == 2) ? flags[0] : outmode;
  long i = (long)blockIdx.x * blockDim.x + threadIdx.x;
  long stride = (long)gridDim.x * blockDim.x;
  long n = (long)NN * DD;
  const float invN = 1.0f / (float)NN;
  for (; i < n; i += stride){
    int c = (int)(i & 511);
    float m = sum[c] * invN;
    float var = sumsq[c] * invN - m * m;
    float v = (T[i] - m) * rsqrtf(var + BNEPS) * g[c] + b[c];
    if (addsrc) v += load1(addsrc, i, am);
    store1(out, i, om, v);
    if (out2) out2[i] = f2bf(v);
  }
}

__global__ void zero_out_bf16(void* out, long nbytes){
  long i = (long)blockIdx.x * blockDim.x + threadIdx.x;
  long stride = (long)gridDim.x * blockDim.x;
  long n = nbytes / 2;
  for (; i < n; i += stride) ((unsigned short*)out)[i] = 0;
}

// ---------------- MFMA bf16 GEMM: C = act(A@Bt^T + bias) (+ addsrc) ----------------
// BK=64 K-step (Kd must be multiple of 64). XOR-swizzle slot^=(row&7), both sides.
__global__ __launch_bounds__(256) void gemm_mfma(
    const unsigned short* __restrict__ A, const unsigned short* __restrict__ Bt,
    void* __restrict__ C, int M, int N, int Kd, int lda, int ldc,
    const float* __restrict__ bias, const void* __restrict__ addsrc, int dorelu,
    int addmode, int cmode, const int* __restrict__ flags){
  int fl = flags[0];
  int adbf = (addmode == 2) ? fl : addmode;
  int cbf = (cmode == 2) ? fl : cmode;
  __shared__ unsigned short Asl[128 * 64];
  __shared__ unsigned short Bsl[128 * 64];
  const int tid = threadIdx.x;

  int nx = gridDim.x;
  int nwg = nx * gridDim.y;
  int p = blockIdx.y * nx + blockIdx.x;
  int q8 = nwg >> 3, r8 = nwg & 7;
  int xcd = p & 7, off = p >> 3;
  int id = (xcd < r8 ? xcd * (q8 + 1) : r8 * (q8 + 1) + (xcd - r8) * q8) + off;
  int by = id / nx, bx = id - by * nx;
  const int bm = by * 128, bn = bx * 128;

  const int lane = tid & 63, wave = tid >> 6;
  const int wm = (wave & 1) * 64, wn = (wave >> 1) * 64;
  const int q = lane >> 4, l16 = lane & 15;
  floatx4 acc[4][4];
#pragma unroll
  for (int i = 0; i < 4; i++)
#pragma unroll
    for (int j = 0; j < 4; j++)
#pragma unroll
      for (int r = 0; r < 4; r++) acc[i][j][r] = 0.f;

  const int sbase = wave << 8;   // 256 slots/wave (1024 slots = 128 rows x 8)

  for (int k0 = 0; k0 < Kd; k0 += 64){
    __syncthreads();
#pragma unroll
    for (int pp = 0; pp < 4; pp++){
      int slot = sbase + (pp << 6) + lane;
      int row = slot >> 3;
      int ssl = (slot & 7) ^ (row & 7);       // inverse-swizzled source slot
      int rA = bm + row; if (rA > M - 1) rA = M - 1;
      gload16(A + (long)rA * lda + k0 + (ssl << 3), &Asl[(sbase + (pp << 6)) << 3]);
      gload16(Bt + (long)(bn + row) * Kd + k0 + (ssl << 3), &Bsl[(sbase + (pp << 6)) << 3]);
    }
    __syncthreads();
#pragma unroll
    for (int kk = 0; kk < 2; kk++){
      short8 af[4], bfr[4];
#pragma unroll
      for (int i = 0; i < 4; i++){
        int ra = wm + i * 16 + l16;
        af[i] = *(const short8*)&Asl[(ra << 6) + ((((kk << 2) + q) ^ (ra & 7)) << 3)];
        int rb = wn + i * 16 + l16;
        bfr[i] = *(const short8*)&Bsl[(rb << 6) + ((((kk << 2) + q) ^ (rb & 7)) << 3)];
      }
#pragma unroll
      for (int i = 0; i < 4; i++)
#pragma unroll
        for (int j = 0; j < 4; j++)
          acc[i][j] = __builtin_amdgcn_mfma_f32_16x16x32_bf16(af[i], bfr[j], acc[i][j], 0, 0, 0);
    }
  }
#pragma unroll
  for (int i = 0; i < 4; i++){
#pragma unroll
    for (int r = 0; r < 4; r++){
      int row = bm + wm + i * 16 + q * 4 + r;
      if (row >= M) continue;
#pragma unroll
      for (int j = 0; j < 4; j++){
        int col = bn + wn + j * 16 + l16;
        float v = acc[i][j][r];
        if (bias) v += bias[col];
        if (dorelu) v = fmaxf(v, 0.f);
        if (addsrc) v += load1(addsrc, (long)row * ldc + col, adbf);
        store1(C, (long)row * ldc + col, cbf, v);
      }
    }
  }
}

// ---- MFMA GEMM with TRANSPOSED bf16 output: Ct[col][row], ldct-strided ----
// BK=64; staging LDS unioned with epilogue staging (33 KB total).
__global__ __launch_bounds__(256) void gemm_mfma_t(
    const unsigned short* __restrict__ A, const unsigned short* __restrict__ Bt,
    unsigned short* __restrict__ Ct, int M, int Kd, int lda, int ldct,
    const float* __restrict__ bias, int dorelu){
  __shared__ unsigned short lds[16896];   // A[0:8192) B[8192:16384); epilogue sc[0:16896)
  unsigned short* Asl = lds;
  unsigned short* Bsl = lds + 8192;
  const int tid = threadIdx.x;

  int nx = gridDim.x;
  int nwg = nx * gridDim.y;
  int p = blockIdx.y * nx + blockIdx.x;
  int q8 = nwg >> 3, r8 = nwg & 7;
  int xcd = p & 7, off = p >> 3;
  int id = (xcd < r8 ? xcd * (q8 + 1) : r8 * (q8 + 1) + (xcd - r8) * q8) + off;
  int by = id / nx, bx = id - by * nx;
  const int bm = by * 128, bn = bx * 128;

  const int lane = tid & 63, wave = tid >> 6;
  const int wm = (wave & 1) * 64, wn = (wave >> 1) * 64;
  const int q = lane >> 4, l16 = lane & 15;
  floatx4 acc[4][4];
#pragma unroll
  for (int i = 0; i < 4; i++)
#pragma unroll
    for (int j = 0; j < 4; j++)
#pragma unroll
      for (int r = 0; r < 4; r++) acc[i][j][r] = 0.f;

  const int sbase = wave << 8;

  for (int k0 = 0; k0 < Kd; k0 += 64){
    __syncthreads();
#pragma unroll
    for (int pp = 0; pp < 4; pp++){
      int slot = sbase + (pp << 6) + lane;
      int row = slot >> 3;
      int ssl = (slot & 7) ^ (row & 7);
      int rA = bm + row; if (rA > M - 1) rA = M - 1;
      gload16(A + (long)rA * lda + k0 + (ssl << 3), &Asl[(sbase + (pp << 6)) << 3]);
      gload16(Bt + (long)(bn + row) * Kd + k0 + (ssl << 3), &Bsl[(sbase + (pp << 6)) << 3]);
    }
    __syncthreads();
#pragma unroll
    for (int kk = 0; kk < 2; kk++){
      short8 af[4], bfr[4];
#pragma unroll
      for (int i = 0; i < 4; i++){
        int ra = wm + i * 16 + l16;
        af[i] = *(const short8*)&Asl[(ra << 6) + ((((kk << 2) + q) ^ (ra & 7)) << 3)];
        int rb = wn + i * 16 + l16;
        bfr[i] = *(const short8*)&Bsl[(rb << 6) + ((((kk << 2) + q) ^ (rb & 7)) << 3)];
      }
#pragma unroll
      for (int i = 0; i < 4; i++)
#pragma unroll
        for (int j = 0; j < 4; j++)
          acc[i][j] = __builtin_amdgcn_mfma_f32_16x16x32_bf16(af[i], bfr[j], acc[i][j], 0, 0, 0);
    }
  }
  __syncthreads();   // all waves done with staging region before sc overwrite
  // stage C^T into LDS (pitch 132 keeps 8B alignment + conflict-free)
#pragma unroll
  for (int i = 0; i < 4; i++){
#pragma unroll
    for (int j = 0; j < 4; j++){
      int lr0 = wm + i * 16 + q * 4;
      int lc = wn + j * 16 + l16;
      float v0 = acc[i][j][0], v1 = acc[i][j][1], v2 = acc[i][j][2], v3 = acc[i][j][3];
      if (bias){ float bb = bias[bn + lc]; v0 += bb; v1 += bb; v2 += bb; v3 += bb; }
      if (dorelu){
        v0 = fmaxf(v0, 0.f); v1 = fmaxf(v1, 0.f);
        v2 = fmaxf(v2, 0.f); v3 = fmaxf(v3, 0.f);
      }
      ushort4 pk;
      pk.x = f2bf(v0); pk.y = f2bf(v1); pk.z = f2bf(v2); pk.w = f2bf(v3);
      *(ushort4*)&lds[lc * 132 + lr0] = pk;
    }
  }
  __syncthreads();
  // coalesced transposed store
#pragma unroll
  for (int pp = 0; pp < 8; pp++){
    int idx = pp * 2048 + tid * 8;
    int r2 = idx >> 7, c2 = idx & 127;
    int gc = bm + c2;
    if (gc >= ldct) continue;
    short8 o;
#pragma unroll
    for (int e = 0; e < 8; e++)
      ((unsigned short*)&o)[e] = (gc + e < M) ? lds[r2 * 132 + c2 + e] : (unsigned short)0;
    *(short8*)&Ct[(long)(bn + r2) * ldct + gc] = o;
  }
}

// ---- split-K MFMA NT: P[z][128][512] = A[128][KPAD] @ Bt[512][KPAD]^T partials ----
__global__ __launch_bounds__(256) void gemm_sk(
    const unsigned short* __restrict__ A, const unsigned short* __restrict__ Bt,
    float* __restrict__ P, int ldk){
  __shared__ unsigned short Asl[128 * 32];
  __shared__ unsigned short Bsl[128 * 32];
  const int tid = threadIdx.x;
  const int bn = blockIdx.x * 128;
  const int ks = blockIdx.z * SKE;
  const int ke = min(ks + SKE, KPAD);

  const int lane = tid & 63, wave = tid >> 6;
  const int wm = (wave & 1) * 64, wn = (wave >> 1) * 64;
  const int q = lane >> 4, l16 = lane & 15;
  const int swz = (q ^ ((l16 >> 1) & 3)) << 3;
  floatx4 acc[4][4];
#pragma unroll
  for (int i = 0; i < 4; i++)
#pragma unroll
    for (int j = 0; j < 4; j++)
#pragma unroll
      for (int r = 0; r < 4; r++) acc[i][j][r] = 0.f;

  const int sbase = wave << 7;

  for (int k0 = ks; k0 < ke; k0 += 32){
    __syncthreads();
#pragma unroll
    for (int pp = 0; pp < 2; pp++){
      int slot = sbase + (pp << 6) + lane;
      int row = slot >> 2;
      int ssl = (slot & 3) ^ ((slot >> 3) & 3);
      gload16(A + (long)row * ldk + k0 + (ssl << 3), &Asl[(sbase + (pp << 6)) << 3]);
      gload16(Bt + (long)(bn + row) * ldk + k0 + (ssl << 3), &Bsl[(sbase + (pp << 6)) << 3]);
    }
    __syncthreads();
    short8 af[4], bfr[4];
#pragma unroll
    for (int i = 0; i < 4; i++){
      int ra = wm + i * 16 + l16;
      af[i] = *(const short8*)&Asl[(ra << 5) + swz];
      int rb = wn + i * 16 + l16;
      bfr[i] = *(const short8*)&Bsl[(rb << 5) + swz];
    }
#pragma unroll
    for (int i = 0; i < 4; i++)
#pragma unroll
      for (int j = 0; j < 4; j++)
        acc[i][j] = __builtin_amdgcn_mfma_f32_16x16x32_bf16(af[i], bfr[j], acc[i][j], 0, 0, 0);
  }
  long base = (long)blockIdx.z * (KE * DD);
#pragma unroll
  for (int i = 0; i < 4; i++){
#pragma unroll
    for (int r = 0; r < 4; r++){
      int row = wm + i * 16 + q * 4 + r;
#pragma unroll
      for (int j = 0; j < 4; j++){
        int col = bn + wn + j * 16 + l16;
        P[base + (long)row * DD + col] = acc[i][j][r];
      }
    }
  }
}

__global__ void reduce_part(const float* __restrict__ P, float* __restrict__ C){
  int i = blockIdx.x * 256 + threadIdx.x;   // grid 256 -> 65536 elems
  float s = 0.f;
  for (int z = 0; z < ZC; z++) s += P[(long)z * (KE * DD) + i];
  C[i] = s;
}

// evsum[k] = sum_n EVb[n][k]
__global__ __launch_bounds__(256) void evsum_kernel(const unsigned short* __restrict__ EVb,
                                                    float* __restrict__ evsum){
  int b = blockIdx.x, t = threadIdx.x;
  int k = t & 127, half = t >> 7;
  float s = 0.f;
  for (int r = 0; r < 128; r += 2){
    int row = b * 128 + r + half;
    if (row < NN) s += bf2f(EVb[(long)row * KE + k]);
  }
  atomicAdd(&evsum[k], s);
}

// Ut[c][k] = filt(k, c>>7) * ( dot(XU[k,:], W2t[c,:]) + evsum[k]*b2[c] )
__global__ __launch_bounds__(256) void wave_mix(
    const float* __restrict__ XU, const unsigned short* __restrict__ W2t,
    const float* __restrict__ evsum, const float* __restrict__ b2,
    const float* __restrict__ filt, unsigned short* __restrict__ Ut){
  int i = blockIdx.x * 256 + threadIdx.x;   // grid 256 -> 65536
  int k = i >> 9, c = i & 511;
  float acc = evsum[k] * b2[c];
  const float* xr = XU + (long)k * DD;
  const unsigned short* wr = W2t + (long)c * DD;
#pragma unroll 4
  for (int d = 0; d < DD; d += 8){
    float4 x0 = *(const float4*)(xr + d);
    float4 x1 = *(const float4*)(xr + d + 4);
    ushort4 w0 = *(const ushort4*)(wr + d);
    ushort4 w1 = *(const ushort4*)(wr + d + 4);
    acc += x0.x * bf2f(w0.x) + x0.y * bf2f(w0.y) + x0.z * bf2f(w0.z) + x0.w * bf2f(w0.w)
         + x1.x * bf2f(w1.x) + x1.y * bf2f(w1.y) + x1.z * bf2f(w1.z) + x1.w * bf2f(w1.w);
  }
  float v = acc * filt[k * TJN + (c >> 7)];
  Ut[(long)c * KE + k] = f2bf(v);
}

// M2t[j][k] = sum_c (U2[k][c] * filt[k][c>>7]) * Wft[j][c]   (folds COMB into fusion)
__global__ __launch_bounds__(256) void mix2(
    const float* __restrict__ U2, const unsigned short* __restrict__ Wft,
    const float* __restrict__ filt, unsigned short* __restrict__ M2t){
  int i = blockIdx.x * 256 + threadIdx.x;   // grid 256 -> 65536
  int k = i & 127, j = i >> 7;
  float fs0 = filt[k * TJN + 0], fs1 = filt[k * TJN + 1];
  float fs2 = filt[k * TJN + 2], fs3 = filt[k * TJN + 3];
  const float* ur = U2 + (long)k * DD;
  const unsigned short* wr = Wft + (long)j * DD;
  float acc = 0.f;
#pragma unroll
  for (int t = 0; t < 4; t++){
    float a = 0.f;
    for (int c = t * 128; c < t * 128 + 128; c += 8){
      float4 x0 = *(const float4*)(ur + c);
      float4 x1 = *(const float4*)(ur + c + 4);
      ushort4 w0 = *(const ushort4*)(wr + c);
      ushort4 w1 = *(const ushort4*)(wr + c + 4);
      a += x0.x * bf2f(w0.x) + x0.y * bf2f(w0.y) + x0.z * bf2f(w0.z) + x0.w * bf2f(w0.w)
         + x1.x * bf2f(w1.x) + x1.y * bf2f(w1.y) + x1.z * bf2f(w1.z) + x1.w * bf2f(w1.w);
    }
    acc += (t == 0 ? fs0 : t == 1 ? fs1 : t == 2 ? fs2 : fs3) * a;
  }
  M2t[(long)j * KE + k] = f2bf(acc);
}

// ---------------- host orchestration ----------------
extern "C" void kernel_launch(void* const* d_in, const int* in_sizes, int n_in,
                              void* d_out, int out_size, void* d_ws, size_t ws_size,
                              hipStream_t stream){
  const int E = in_sizes[1] / 2;
  const long NB = (long)NN * DD;
  float* ws = (float*)d_ws;
  (void)n_in;

  size_t cur = 0;
  auto alloc = [&](size_t n){ size_t o = cur; cur += (n + 63) & ~(size_t)63; return o; };

  size_t o_flags = alloc(64);
  size_t o_zero  = cur;                      // ---- zeroed region ----
  size_t o_U     = alloc((size_t)KE * DD);
  size_t o_U2    = alloc((size_t)KE * DD);
  size_t o_stats = alloc(6 * DD);
  size_t o_evsum = alloc(KE);
  size_t o_ideg  = alloc(NN);
  size_t o_cur   = alloc(NN);
  size_t zlen    = cur - o_zero;             // -----------------------
  size_t o_dinv  = alloc(NN);
  size_t o_rowp  = alloc(NN + 64);
  size_t o_filt  = alloc(KE * TJN);          // contiguous param block start
  size_t o_bgcn  = alloc(DD);
  size_t o_b2    = alloc(DD);
  size_t o_bfus  = alloc(DD);
  size_t o_bff1  = alloc(2 * DD);
  size_t o_bff2  = alloc(DD);
  size_t o_bn    = alloc(6 * DD);            // contiguous param block end
  size_t o_Wgt   = alloc((size_t)DD * DD / 2);
  size_t o_W2t   = alloc((size_t)DD * DD / 2);
  size_t o_Wft   = alloc((size_t)DD * DD / 2);
  size_t o_W1t   = alloc((size_t)DD * DD);          // [1024][512] bf16
  size_t o_Wff2t = alloc((size_t)DD * DD);          // [512][1024] bf16
  size_t o_Ut    = alloc((size_t)KE * DD / 2);
  size_t o_M2t   = alloc((size_t)KE * DD / 2);      // [512][128] bf16
  size_t o_idx   = alloc((size_t)2 * E);
  size_t o_csr   = alloc((size_t)E);
  size_t o_part  = alloc((size_t)ZC * KE * DD);     // split-K partials (16.8 MB)
  size_t o_BF    = alloc(NB);                       // fp32 N x D (also hosts XbT/EVbT early)
  size_t o_BA    = alloc(NB / 2);                   // bf16 N x D (also hosts VAt)
  size_t o_BHL   = alloc(NB / 2);                   // bf16 N x D; BA+BHL = F1 [N,1024]
  size_t o_Xb    = alloc(NB / 2);                   // bf16 copy of x
  size_t o_EVb   = alloc((size_t)NN * KE / 2);      // bf16 copy of eigenvector
  size_t o_Hb    = alloc(NB / 2);                   // bf16 copy of h

  if (cur * 4 > ws_size){
    zero_out_bf16<<<2048, 256, 0, stream>>>(d_out, (long)out_size * 2);
    return;
  }

  int* flags = (int*)(ws + o_flags);
  float* BF  = ws + o_BF;
  void* BA   = (void*)(ws + o_BA);
  void* BHL  = (void*)(ws + o_BHL);
  void* F1   = BA;
  int* srcv  = (int*)(ws + o_idx);
  int* dstv  = srcv + E;
  int* ideg  = (int*)(ws + o_ideg);
  int* cursor= (int*)(ws + o_cur);
  int* rowp  = (int*)(ws + o_rowp);
  int* csr   = (int*)(ws + o_csr);
  float* dinv= ws + o_dinv;
  float* U   = ws + o_U;
  float* U2  = ws + o_U2;
  float* st  = ws + o_stats;
  float* Part= ws + o_part;
  unsigned short* Wgt   = (unsigned short*)(ws + o_Wgt);
  unsigned short* W2t   = (unsigned short*)(ws + o_W2t);
  unsigned short* Wft   = (unsigned short*)(ws + o_Wft);
  unsigned short* W1t   = (unsigned short*)(ws + o_W1t);
  unsigned short* Wff2t = (unsigned short*)(ws + o_Wff2t);
  unsigned short* Ut    = (unsigned short*)(ws + o_Ut);
  unsigned short* M2t   = (unsigned short*)(ws + o_M2t);
  unsigned short* Xb    = (unsigned short*)(ws + o_Xb);
  unsigned short* EVb   = (unsigned short*)(ws + o_EVb);
  unsigned short* Hb    = (unsigned short*)(ws + o_Hb);
  // transposed-K operands live in the BF region until the fusion GEMM needs BF:
  // XbT [512][KPAD] = 12,804,096 floats; EVbT [128][KPAD] starts at +12,804,160.
  unsigned short* XbT  = (unsigned short*)(ws + o_BF);
  unsigned short* EVbT = (unsigned short*)(ws + o_BF + 12804160);
  unsigned short* VAt  = (unsigned short*)BA;       // [512][KPAD] (tail spills into BHL; dead before BHL use)

  detect_kernel<<<1, 64, 0, stream>>>(d_in[0], d_in[1], flags);
  hipMemsetAsync(ws + o_zero, 0, zlen * 4, stream);

  P13 pp;
  pp.p[0] = d_in[3];  pp.p[1] = d_in[5];  pp.p[2] = d_in[7];  pp.p[3] = d_in[9];
  pp.p[4] = d_in[17]; pp.p[5] = d_in[19];
  for (int i = 0; i < 6; i++) pp.p[6 + i] = d_in[10 + i];
  cvt_params<<<26, 256, 0, stream>>>(pp, ws + o_filt, flags);

  // fused straight-bf16 + padded-transpose conversions
  cvt_bt<<<dim3(8, 782), 256, 0, stream>>>(d_in[0], Xb,  XbT,  NN, DD, KPAD, flags);
  cvt_bt<<<dim3(2, 782), 256, 0, stream>>>(d_in[2], EVb, EVbT, NN, KE, KPAD, flags);
  // weight transposes (coalesced both sides)
  cvt_t<<<dim3(8, 8),   256, 0, stream>>>(d_in[4],  Wgt,   DD, DD, DD, 0, 0, 2, flags);
  cvt_t<<<dim3(2, 8, 4),256, 0, stream>>>(d_in[6],  W2t,   DD, 128, DD,
                                          (long)DD * 128, (long)128 * DD, 2, flags);
  cvt_t<<<dim3(8, 8),   256, 0, stream>>>(d_in[8],  Wft,   DD, DD, DD, 0, 0, 2, flags);
  cvt_t<<<dim3(16, 8),  256, 0, stream>>>(d_in[16], W1t,   DD, 2 * DD, DD, 0, 0, 2, flags);
  cvt_t<<<dim3(8, 16),  256, 0, stream>>>(d_in[18], Wff2t, 2 * DD, DD, 2 * DD, 0, 0, 2, flags);
  cvt_idx<<<4096, 256, 0, stream>>>(d_in[1], srcv, 2L * E, flags);

  // CSR build
  deg_kernel<<<(E + 255) / 256, 256, 0, stream>>>(dstv, ideg, E);
  scan_kernel<<<1, 1024, 0, stream>>>(ideg, rowp, E);
  dinv_kernel<<<(NN + 255) / 256, 256, 0, stream>>>(ideg, dinv);
  scatter_kernel<<<(E + 255) / 256, 256, 0, stream>>>(srcv, dstv, rowp, cursor, csr, E);

  const int MT = (NN + 127) / 128;   // 391
  dim3 blk(256);
  const void* Xr = d_in[0];

  // ---- global WaveGC branch (first: BF region still holds XbT/EVbT) ----
  gemm_sk<<<dim3(4, 1, ZC), blk, 0, stream>>>(EVbT, XbT, Part, KPAD);               // proj1
  reduce_part<<<256, 256, 0, stream>>>(Part, U);                                    // XU fp32
  evsum_kernel<<<MT, 256, 0, stream>>>(EVb, ws + o_evsum);
  wave_mix<<<256, 256, 0, stream>>>(U, W2t, ws + o_evsum, ws + o_b2,
                                    ws + o_filt, Ut);                               // -> Ut bf16
  gemm_mfma_t<<<dim3(4, MT), blk, 0, stream>>>(EVb, Ut, VAt, NN, KE, KE, KPAD,
                                               nullptr, 1);                         // V^T bf16
  gemm_sk<<<dim3(4, 1, ZC), blk, 0, stream>>>(EVbT, VAt, Part, KPAD);               // proj2
  reduce_part<<<256, 256, 0, stream>>>(Part, U2);
  mix2<<<256, 256, 0, stream>>>(U2, Wft, ws + o_filt, M2t);                         // COMB folded
  gemm_mfma<<<dim3(4, MT), blk, 0, stream>>>(EVb, M2t, BF, NN, DD, KE, KE, DD,
                                             ws + o_bfus, Xr, 1, 2, 0, flags);      // relu+X fp32
  bn_stats<<<MT, 512, 0, stream>>>(BF, st + 2 * DD, st + 3 * DD);
  bn_apply<<<4096, 256, 0, stream>>>(BF, st + 2 * DD, st + 3 * DD,
                                     ws + o_bn + 2 * DD, ws + o_bn + 3 * DD,
                                     nullptr, 0, BHL, 1, nullptr, flags);           // h_attn bf16

  // ---- local GCN branch ----
  gemm_mfma<<<dim3(4, MT), blk, 0, stream>>>(Xb, Wgt, BA, NN, DD, DD, DD, DD,
                                             nullptr, nullptr, 0, 0, 1, flags);     // xw bf16
  gcn_gather<<<NN, 64, 0, stream>>>(rowp, csr, dinv, BA, Xr, ws + o_bgcn, BF, flags);
  bn_stats<<<MT, 512, 0, stream>>>(BF, st + 0, st + DD);
  bn_apply<<<4096, 256, 0, stream>>>(BF, st + 0, st + DD,
                                     ws + o_bn + 0 * DD, ws + o_bn + 1 * DD,
                                     BHL, 1, BF, 0, Hb, flags);                     // h fp32 + bf16

  // ---- FFN ----
  gemm_mfma<<<dim3(8, MT), blk, 0, stream>>>(Hb, W1t, F1, NN, 2 * DD, DD, DD, 2 * DD,
                                             ws + o_bff1, nullptr, 1, 0, 1, flags); // F1 bf16
  gemm_mfma<<<dim3(4, MT), blk, 0, stream>>>((const unsigned short*)F1, Wff2t, BF,
                                             NN, DD, 2 * DD, 2 * DD, DD,
                                             ws + o_bff2, BF, 0, 0, 0, flags);      // ff2 + h
  bn_stats<<<MT, 512, 0, stream>>>(BF, st + 4 * DD, st + 5 * DD);
  bn_apply<<<4096, 256, 0, stream>>>(BF, st + 4 * DD, st + 5 * DD,
                                     ws + o_bn + 4 * DD, ws + o_bn + 5 * DD,
                                     nullptr, 0, d_out, 2, nullptr, flags);         // -> out
}

// Round 7
// 1741.575 us; speedup vs baseline: 1.0496x; 1.0496x over previous
//
#include <hip/hip_runtime.h>
#include <hip/hip_bf16.h>

#define NN 50000
#define DD 512
#define KE 128
#define TJN 4
#define BNEPS 1e-5f
#define ZC 64       // split-K chunks
#define KPAD 50016  // NN padded to mult of 32 (zero-filled in transposed operands)
#define SKE 800     // K-elems per split-K chunk (25 steps of 32; 64*800 >= KPAD)

typedef __attribute__((ext_vector_type(8))) short short8;
typedef __attribute__((ext_vector_type(4))) float floatx4;

__device__ __forceinline__ float bf2f(unsigned short h){
  return __uint_as_float(((unsigned int)h) << 16);
}
__device__ __forceinline__ unsigned short f2bf(float f){
  unsigned int u = __float_as_uint(f);
  unsigned int r = (u + 0x7FFF + ((u >> 16) & 1)) >> 16;
  return (unsigned short)r;
}
__device__ __forceinline__ float load1(const void* p, long i, int bf){
  if (bf) return bf2f(((const unsigned short*)p)[i]);
  return ((const float*)p)[i];
}
__device__ __forceinline__ void store1(void* p, long i, int bf, float v){
  if (bf) ((unsigned short*)p)[i] = f2bf(v);
  else ((float*)p)[i] = v;
}

// async global->LDS 16B (dest = wave-uniform base + lane*16)
typedef __attribute__((address_space(3))) unsigned int lds_uint_t;
typedef __attribute__((address_space(1))) unsigned int gbl_uint_t;
__device__ __forceinline__ void gload16(const void* gp, void* lp){
  __builtin_amdgcn_global_load_lds((const gbl_uint_t*)gp, (lds_uint_t*)lp, 16, 0, 0);
}

// ---------------- dtype sniffing ----------------
__global__ void detect_kernel(const void* xraw, const void* eraw, int* flags){
  if (blockIdx.x == 0 && threadIdx.x == 0){
    const unsigned short* p = (const unsigned short*)xraw;
    int cnt = 0;
    for (int i = 0; i < 128; i++){
      int e = (p[i] >> 7) & 0xFF;
      if (e >= 110 && e <= 133) cnt++;
    }
    flags[0] = (cnt >= 96) ? 1 : 0;
    const unsigned int* q = (const unsigned int*)eraw;
    int z = 0;
    for (int i = 0; i < 64; i++) if (q[2*i+1] == 0u) z++;
    flags[1] = (z >= 48) ? 1 : 0;
  }
}

// all small parameter vectors in one launch; dst layout matches alloc order:
// [filt 512][bgcn 512][b2 512][bfus 512][bff1 1024][bff2 512][bn 6x512]
struct P13 { const void* p[12]; };
__global__ void cvt_params(P13 pp, float* __restrict__ dst, const int* __restrict__ flags){
  int bf = flags[0];
  int i = blockIdx.x * 256 + threadIdx.x;
  if (i >= 6656) return;
  const void* s; int off;
  if (i < 2048){ s = pp.p[i >> 9]; off = i & 511; }
  else if (i < 3072){ s = pp.p[4]; off = i - 2048; }
  else if (i < 3584){ s = pp.p[5]; off = i - 3072; }
  else { int j = (i - 3584) >> 9; s = pp.p[6 + j]; off = (i - 3584) & 511; }
  dst[i] = load1(s, off, bf);
}

// fused: read raw src[K][Nc] (dtype per flags), write straight bf16 dst1[K][Nc]
// AND transposed bf16 dst2[Nc][ldK] with zero-fill for cols in [K, ldK).
__global__ __launch_bounds__(256) void cvt_bt(
    const void* __restrict__ src, unsigned short* __restrict__ dst1,
    unsigned short* __restrict__ dst2, int K, int Nc, int ldK,
    const int* __restrict__ flags){
  int bf = flags[0];
  __shared__ unsigned short T[64][66];
  int bk = blockIdx.y * 64, bc = blockIdx.x * 64;
  int tid = threadIdx.x;
#pragma unroll
  for (int p = 0; p < 16; p++){
    int idx = p * 256 + tid;
    int r = idx >> 6, c = idx & 63;
    unsigned short h = 0;
    if (bk + r < K){
      h = f2bf(load1(src, (long)(bk + r) * Nc + bc + c, bf));
      dst1[(long)(bk + r) * Nc + bc + c] = h;
    }
    T[r][c] = h;
  }
  __syncthreads();
#pragma unroll
  for (int p = 0; p < 16; p++){
    int idx = p * 256 + tid;
    int r = idx >> 6, c = idx & 63;
    if (bk + c < ldK)
      dst2[(long)(bc + r) * ldK + bk + c] = T[c][r];
  }
}

// tiled transpose+cvt: dst[Nc][ldK] (bf16) = src[K][Nc]; zero-fills dst cols in [K, ldK).
__global__ __launch_bounds__(256) void cvt_t(
    const void* __restrict__ src, unsigned short* __restrict__ dst,
    int K, int Nc, int ldK, long srcz, long dstz, int smode,
    const int* __restrict__ flags){
  int bf = (smode == 2) ? flags[0] : smode;
  __shared__ unsigned short T[64][66];
  int bk = blockIdx.y * 64, bc = blockIdx.x * 64;
  long so = (long)blockIdx.z * srcz;
  long dof = (long)blockIdx.z * dstz;
  int tid = threadIdx.x;
#pragma unroll
  for (int p = 0; p < 16; p++){
    int idx = p * 256 + tid;
    int r = idx >> 6, c = idx & 63;
    float v = 0.f;
    if (bk + r < K) v = load1(src, so + (long)(bk + r) * Nc + bc + c, bf);
    T[r][c] = f2bf(v);
  }
  __syncthreads();
#pragma unroll
  for (int p = 0; p < 16; p++){
    int idx = p * 256 + tid;
    int r = idx >> 6, c = idx & 63;
    if (bk + c < ldK)
      dst[dof + (long)(bc + r) * ldK + bk + c] = T[c][r];
  }
}

__global__ void cvt_idx(const void* __restrict__ src, int* __restrict__ dst,
                        long n, const int* __restrict__ flags){
  int w64 = flags[1];
  long i = (long)blockIdx.x * blockDim.x + threadIdx.x;
  long stride = (long)gridDim.x * blockDim.x;
  for (; i < n; i += stride)
    dst[i] = w64 ? (int)((const long long*)src)[i] : ((const int*)src)[i];
}

// ---------------- CSR build ----------------
__global__ void deg_kernel(const int* __restrict__ dst, int* __restrict__ deg, int E){
  int i = blockIdx.x * blockDim.x + threadIdx.x;
  if (i < E) atomicAdd(&deg[dst[i]], 1);
}

__global__ __launch_bounds__(1024) void scan_kernel(const int* __restrict__ deg,
                                                    int* __restrict__ rowptr, int E){
  __shared__ int lds[1024];
  int t = threadIdx.x;
  const int CH = (NN + 1023) / 1024;   // 49
  int base = t * CH;
  int s = 0;
  for (int i = 0; i < CH; i++){
    int idx = base + i;
    if (idx < NN) s += deg[idx];
  }
  lds[t] = s;
  __syncthreads();
  for (int off = 1; off < 1024; off <<= 1){
    int v = (t >= off) ? lds[t - off] : 0;
    __syncthreads();
    lds[t] += v;
    __syncthreads();
  }
  int ex = (t == 0) ? 0 : lds[t - 1];
  for (int i = 0; i < CH; i++){
    int idx = base + i;
    if (idx < NN){ rowptr[idx] = ex; ex += deg[idx]; }
  }
  if (t == 1023) rowptr[NN] = ex;
}

__global__ void dinv_kernel(const int* __restrict__ deg, float* __restrict__ dinv){
  int i = blockIdx.x * blockDim.x + threadIdx.x;
  if (i < NN) dinv[i] = rsqrtf((float)deg[i] + 1.0f);
}

__global__ void scatter_kernel(const int* __restrict__ srcv, const int* __restrict__ dstv,
                               const int* __restrict__ rowptr, int* __restrict__ cursor,
                               int* __restrict__ csr, int E){
  int i = blockIdx.x * blockDim.x + threadIdx.x;
  if (i < E){
    int d = dstv[i];
    int pos = atomicAdd(&cursor[d], 1);
    csr[rowptr[d] + pos] = srcv[i];
  }
}

// ---------------- fused GCN gather (agg + self-loop + residual + bias) ----------------
__global__ __launch_bounds__(64) void gcn_gather(
    const int* __restrict__ rowptr, const int* __restrict__ csr,
    const float* __restrict__ dinv, const void* __restrict__ xw /*bf16*/,
    const void* __restrict__ X, const float* __restrict__ bias,
    float* __restrict__ out, const int* __restrict__ flags){
  int d = blockIdx.x;
  int lane = threadIdx.x;
  __shared__ int s_idx[64];
  __shared__ float s_dv[64];
  int start = rowptr[d], end = rowptr[d + 1];
  float dd = dinv[d];
  float acc[8];
#pragma unroll
  for (int k = 0; k < 8; k++) acc[k] = 0.f;
  const unsigned short* xwp = (const unsigned short*)xw;
  int c0 = lane * 8;
  for (int j0 = start; j0 < end; j0 += 64){
    int cnt = min(64, end - j0);
    __syncthreads();
    if (lane < cnt){
      int s = csr[j0 + lane];
      s_idx[lane] = s;
      s_dv[lane] = dinv[s];
    }
    __syncthreads();
    for (int t = 0; t < cnt; t++){
      int s = s_idx[t];
      float nm = dd * s_dv[t];
      union { float4 f; unsigned short u[8]; } r;
      r.f = *(const float4*)(xwp + (long)s * DD + c0);
#pragma unroll
      for (int k = 0; k < 8; k++) acc[k] += nm * bf2f(r.u[k]);
    }
  }
  int xf = flags[0];
  long base = (long)d * DD + c0;
  union { float4 f; unsigned short u[8]; } sf;
  sf.f = *(const float4*)(xwp + base);
  float d2 = dd * dd;
#pragma unroll
  for (int k = 0; k < 8; k++)
    out[base + k] = load1(X, base + k, xf) + acc[k] + d2 * bf2f(sf.u[k]) + bias[c0 + k];
}

// ---------------- batch norm ----------------
__global__ __launch_bounds__(512) void bn_stats(const float* __restrict__ T,
                                                float* __restrict__ sum,
                                                float* __restrict__ sumsq){
  int c = threadIdx.x;
  long r0 = (long)blockIdx.x * 128;
  float s = 0.f, q = 0.f;
  for (int r = 0; r < 128; r++){
    long rr = r0 + r;
    if (rr < NN){
      float v = T[rr * DD + c];
      s += v; q += v * v;
    }
  }
  atomicAdd(&sum[c], s);
  atomicAdd(&sumsq[c], q);
}

__global__ void bn_apply(const float* __restrict__ T,
                         const float* __restrict__ sum, const float* __restrict__ sumsq,
                         const float* __restrict__ g, const float* __restrict__ b,
                         const void* __restrict__ addsrc, int addmode,
                         void* __restrict__ out, int outmode,
                         unsigned short* __restrict__ out2,
                         const int* __restrict__ flags){
  int am = (addmode == 2) ? flags[0] : addmode;
  int om = (outmode == 2) ? flags[0] : outmode;
  long i = (long)blockIdx.x * blockDim.x + threadIdx.x;
  long stride = (long)gridDim.x * blockDim.x;
  long n = (long)NN * DD;
  const float invN = 1.0f / (float)NN;
  for (; i < n; i += stride){
    int c = (int)(i & 511);
    float m = sum[c] * invN;
    float var = sumsq[c] * invN - m * m;
    float v = (T[i] - m) * rsqrtf(var + BNEPS) * g[c] + b[c];
    if (addsrc) v += load1(addsrc, i, am);
    store1(out, i, om, v);
    if (out2) out2[i] = f2bf(v);
  }
}

__global__ void zero_out_bf16(void* out, long nbytes){
  long i = (long)blockIdx.x * blockDim.x + threadIdx.x;
  long stride = (long)gridDim.x * blockDim.x;
  long n = nbytes / 2;
  for (; i < n; i += stride) ((unsigned short*)out)[i] = 0;
}

// ---------------- MFMA bf16 GEMM: C = act(A@Bt^T + bias) (+ addsrc) ----------------
// BK=32, 16 KB staging LDS (round-5 configuration: occupancy > LDS-deep BK=64).
__global__ __launch_bounds__(256) void gemm_mfma(
    const unsigned short* __restrict__ A, const unsigned short* __restrict__ Bt,
    void* __restrict__ C, int M, int N, int Kd, int lda, int ldc,
    const float* __restrict__ bias, const void* __restrict__ addsrc, int dorelu,
    int addmode, int cmode, const int* __restrict__ flags){
  int fl = flags[0];
  int adbf = (addmode == 2) ? fl : addmode;
  int cbf = (cmode == 2) ? fl : cmode;
  __shared__ unsigned short Asl[128 * 32];
  __shared__ unsigned short Bsl[128 * 32];
  const int tid = threadIdx.x;

  int nx = gridDim.x;
  int nwg = nx * gridDim.y;
  int p = blockIdx.y * nx + blockIdx.x;
  int q8 = nwg >> 3, r8 = nwg & 7;
  int xcd = p & 7, off = p >> 3;
  int id = (xcd < r8 ? xcd * (q8 + 1) : r8 * (q8 + 1) + (xcd - r8) * q8) + off;
  int by = id / nx, bx = id - by * nx;
  const int bm = by * 128, bn = bx * 128;

  const int lane = tid & 63, wave = tid >> 6;
  const int wm = (wave & 1) * 64, wn = (wave >> 1) * 64;
  const int q = lane >> 4, l16 = lane & 15;
  const int swz = (q ^ ((l16 >> 1) & 3)) << 3;
  floatx4 acc[4][4];
#pragma unroll
  for (int i = 0; i < 4; i++)
#pragma unroll
    for (int j = 0; j < 4; j++)
#pragma unroll
      for (int r = 0; r < 4; r++) acc[i][j][r] = 0.f;

  const int sbase = wave << 7;

  for (int k0 = 0; k0 < Kd; k0 += 32){
    __syncthreads();
#pragma unroll
    for (int pp = 0; pp < 2; pp++){
      int slot = sbase + (pp << 6) + lane;
      int row = slot >> 2;
      int ssl = (slot & 3) ^ ((slot >> 3) & 3);
      int rA = bm + row; if (rA > M - 1) rA = M - 1;
      gload16(A + (long)rA * lda + k0 + (ssl << 3), &Asl[(sbase + (pp << 6)) << 3]);
      gload16(Bt + (long)(bn + row) * Kd + k0 + (ssl << 3), &Bsl[(sbase + (pp << 6)) << 3]);
    }
    __syncthreads();
    short8 af[4], bfr[4];
#pragma unroll
    for (int i = 0; i < 4; i++){
      int ra = wm + i * 16 + l16;
      af[i] = *(const short8*)&Asl[(ra << 5) + swz];
      int rb = wn + i * 16 + l16;
      bfr[i] = *(const short8*)&Bsl[(rb << 5) + swz];
    }
#pragma unroll
    for (int i = 0; i < 4; i++)
#pragma unroll
      for (int j = 0; j < 4; j++)
        acc[i][j] = __builtin_amdgcn_mfma_f32_16x16x32_bf16(af[i], bfr[j], acc[i][j], 0, 0, 0);
  }
#pragma unroll
  for (int i = 0; i < 4; i++){
#pragma unroll
    for (int r = 0; r < 4; r++){
      int row = bm + wm + i * 16 + q * 4 + r;
      if (row >= M) continue;
#pragma unroll
      for (int j = 0; j < 4; j++){
        int col = bn + wn + j * 16 + l16;
        float v = acc[i][j][r];
        if (bias) v += bias[col];
        if (dorelu) v = fmaxf(v, 0.f);
        if (addsrc) v += load1(addsrc, (long)row * ldc + col, adbf);
        store1(C, (long)row * ldc + col, cbf, v);
      }
    }
  }
}

// ---- MFMA GEMM with TRANSPOSED bf16 output: Ct[col][row], ldct-strided ----
// BK=32, separate epilogue LDS (round-5 configuration).
__global__ __launch_bounds__(256) void gemm_mfma_t(
    const unsigned short* __restrict__ A, const unsigned short* __restrict__ Bt,
    unsigned short* __restrict__ Ct, int M, int Kd, int lda, int ldct,
    const float* __restrict__ bias, int dorelu){
  __shared__ unsigned short Asl[128 * 32];
  __shared__ unsigned short Bsl[128 * 32];
  __shared__ unsigned short sc[128 * 132];
  const int tid = threadIdx.x;

  int nx = gridDim.x;
  int nwg = nx * gridDim.y;
  int p = blockIdx.y * nx + blockIdx.x;
  int q8 = nwg >> 3, r8 = nwg & 7;
  int xcd = p & 7, off = p >> 3;
  int id = (xcd < r8 ? xcd * (q8 + 1) : r8 * (q8 + 1) + (xcd - r8) * q8) + off;
  int by = id / nx, bx = id - by * nx;
  const int bm = by * 128, bn = bx * 128;

  const int lane = tid & 63, wave = tid >> 6;
  const int wm = (wave & 1) * 64, wn = (wave >> 1) * 64;
  const int q = lane >> 4, l16 = lane & 15;
  const int swz = (q ^ ((l16 >> 1) & 3)) << 3;
  floatx4 acc[4][4];
#pragma unroll
  for (int i = 0; i < 4; i++)
#pragma unroll
    for (int j = 0; j < 4; j++)
#pragma unroll
      for (int r = 0; r < 4; r++) acc[i][j][r] = 0.f;

  const int sbase = wave << 7;

  for (int k0 = 0; k0 < Kd; k0 += 32){
    __syncthreads();
#pragma unroll
    for (int pp = 0; pp < 2; pp++){
      int slot = sbase + (pp << 6) + lane;
      int row = slot >> 2;
      int ssl = (slot & 3) ^ ((slot >> 3) & 3);
      int rA = bm + row; if (rA > M - 1) rA = M - 1;
      gload16(A + (long)rA * lda + k0 + (ssl << 3), &Asl[(sbase + (pp << 6)) << 3]);
      gload16(Bt + (long)(bn + row) * Kd + k0 + (ssl << 3), &Bsl[(sbase + (pp << 6)) << 3]);
    }
    __syncthreads();
    short8 af[4], bfr[4];
#pragma unroll
    for (int i = 0; i < 4; i++){
      int ra = wm + i * 16 + l16;
      af[i] = *(const short8*)&Asl[(ra << 5) + swz];
      int rb = wn + i * 16 + l16;
      bfr[i] = *(const short8*)&Bsl[(rb << 5) + swz];
    }
#pragma unroll
    for (int i = 0; i < 4; i++)
#pragma unroll
      for (int j = 0; j < 4; j++)
        acc[i][j] = __builtin_amdgcn_mfma_f32_16x16x32_bf16(af[i], bfr[j], acc[i][j], 0, 0, 0);
  }
  // stage C^T into LDS (pitch 132 keeps 8B alignment + conflict-free)
#pragma unroll
  for (int i = 0; i < 4; i++){
#pragma unroll
    for (int j = 0; j < 4; j++){
      int lr0 = wm + i * 16 + q * 4;
      int lc = wn + j * 16 + l16;
      float v0 = acc[i][j][0], v1 = acc[i][j][1], v2 = acc[i][j][2], v3 = acc[i][j][3];
      if (bias){ float bb = bias[bn + lc]; v0 += bb; v1 += bb; v2 += bb; v3 += bb; }
      if (dorelu){
        v0 = fmaxf(v0, 0.f); v1 = fmaxf(v1, 0.f);
        v2 = fmaxf(v2, 0.f); v3 = fmaxf(v3, 0.f);
      }
      ushort4 pk;
      pk.x = f2bf(v0); pk.y = f2bf(v1); pk.z = f2bf(v2); pk.w = f2bf(v3);
      *(ushort4*)&sc[lc * 132 + lr0] = pk;
    }
  }
  __syncthreads();
  // coalesced transposed store
#pragma unroll
  for (int pp = 0; pp < 8; pp++){
    int idx = pp * 2048 + tid * 8;
    int r2 = idx >> 7, c2 = idx & 127;
    int gc = bm + c2;
    if (gc >= ldct) continue;
    short8 o;
#pragma unroll
    for (int e = 0; e < 8; e++)
      ((unsigned short*)&o)[e] = (gc + e < M) ? sc[r2 * 132 + c2 + e] : (unsigned short)0;
    *(short8*)&Ct[(long)(bn + r2) * ldct + gc] = o;
  }
}

// ---- split-K MFMA NT: P[z][128][512] = A[128][KPAD] @ Bt[512][KPAD]^T partials ----
__global__ __launch_bounds__(256) void gemm_sk(
    const unsigned short* __restrict__ A, const unsigned short* __restrict__ Bt,
    float* __restrict__ P, int ldk){
  __shared__ unsigned short Asl[128 * 32];
  __shared__ unsigned short Bsl[128 * 32];
  const int tid = threadIdx.x;
  const int bn = blockIdx.x * 128;
  const int ks = blockIdx.z * SKE;
  const int ke = min(ks + SKE, KPAD);

  const int lane = tid & 63, wave = tid >> 6;
  const int wm = (wave & 1) * 64, wn = (wave >> 1) * 64;
  const int q = lane >> 4, l16 = lane & 15;
  const int swz = (q ^ ((l16 >> 1) & 3)) << 3;
  floatx4 acc[4][4];
#pragma unroll
  for (int i = 0; i < 4; i++)
#pragma unroll
    for (int j = 0; j < 4; j++)
#pragma unroll
      for (int r = 0; r < 4; r++) acc[i][j][r] = 0.f;

  const int sbase = wave << 7;

  for (int k0 = ks; k0 < ke; k0 += 32){
    __syncthreads();
#pragma unroll
    for (int pp = 0; pp < 2; pp++){
      int slot = sbase + (pp << 6) + lane;
      int row = slot >> 2;
      int ssl = (slot & 3) ^ ((slot >> 3) & 3);
      gload16(A + (long)row * ldk + k0 + (ssl << 3), &Asl[(sbase + (pp << 6)) << 3]);
      gload16(Bt + (long)(bn + row) * ldk + k0 + (ssl << 3), &Bsl[(sbase + (pp << 6)) << 3]);
    }
    __syncthreads();
    short8 af[4], bfr[4];
#pragma unroll
    for (int i = 0; i < 4; i++){
      int ra = wm + i * 16 + l16;
      af[i] = *(const short8*)&Asl[(ra << 5) + swz];
      int rb = wn + i * 16 + l16;
      bfr[i] = *(const short8*)&Bsl[(rb << 5) + swz];
    }
#pragma unroll
    for (int i = 0; i < 4; i++)
#pragma unroll
      for (int j = 0; j < 4; j++)
        acc[i][j] = __builtin_amdgcn_mfma_f32_16x16x32_bf16(af[i], bfr[j], acc[i][j], 0, 0, 0);
  }
  long base = (long)blockIdx.z * (KE * DD);
#pragma unroll
  for (int i = 0; i < 4; i++){
#pragma unroll
    for (int r = 0; r < 4; r++){
      int row = wm + i * 16 + q * 4 + r;
#pragma unroll
      for (int j = 0; j < 4; j++){
        int col = bn + wn + j * 16 + l16;
        P[base + (long)row * DD + col] = acc[i][j][r];
      }
    }
  }
}

__global__ void reduce_part(const float* __restrict__ P, float* __restrict__ C){
  int i = blockIdx.x * 256 + threadIdx.x;   // grid 256 -> 65536 elems
  float s = 0.f;
  for (int z = 0; z < ZC; z++) s += P[(long)z * (KE * DD) + i];
  C[i] = s;
}

// evsum[k] = sum_n EVb[n][k]
__global__ __launch_bounds__(256) void evsum_kernel(const unsigned short* __restrict__ EVb,
                                                    float* __restrict__ evsum){
  int b = blockIdx.x, t = threadIdx.x;
  int k = t & 127, half = t >> 7;
  float s = 0.f;
  for (int r = 0; r < 128; r += 2){
    int row = b * 128 + r + half;
    if (row < NN) s += bf2f(EVb[(long)row * KE + k]);
  }
  atomicAdd(&evsum[k], s);
}

// Ut[c][k] = filt(k, c>>7) * ( dot(XU[k,:], W2t[c,:]) + evsum[k]*b2[c] )
__global__ __launch_bounds__(256) void wave_mix(
    const float* __restrict__ XU, const unsigned short* __restrict__ W2t,
    const float* __restrict__ evsum, const float* __restrict__ b2,
    const float* __restrict__ filt, unsigned short* __restrict__ Ut){
  int i = blockIdx.x * 256 + threadIdx.x;   // grid 256 -> 65536
  int k = i >> 9, c = i & 511;
  float acc = evsum[k] * b2[c];
  const float* xr = XU + (long)k * DD;
  const unsigned short* wr = W2t + (long)c * DD;
#pragma unroll 4
  for (int d = 0; d < DD; d += 8){
    float4 x0 = *(const float4*)(xr + d);
    float4 x1 = *(const float4*)(xr + d + 4);
    ushort4 w0 = *(const ushort4*)(wr + d);
    ushort4 w1 = *(const ushort4*)(wr + d + 4);
    acc += x0.x * bf2f(w0.x) + x0.y * bf2f(w0.y) + x0.z * bf2f(w0.z) + x0.w * bf2f(w0.w)
         + x1.x * bf2f(w1.x) + x1.y * bf2f(w1.y) + x1.z * bf2f(w1.z) + x1.w * bf2f(w1.w);
  }
  float v = acc * filt[k * TJN + (c >> 7)];
  Ut[(long)c * KE + k] = f2bf(v);
}

// M2t[j][k] = sum_c (U2[k][c] * filt[k][c>>7]) * Wft[j][c]   (folds COMB into fusion)
__global__ __launch_bounds__(256) void mix2(
    const float* __restrict__ U2, const unsigned short* __restrict__ Wft,
    const float* __restrict__ filt, unsigned short* __restrict__ M2t){
  int i = blockIdx.x * 256 + threadIdx.x;   // grid 256 -> 65536
  int k = i & 127, j = i >> 7;
  float fs0 = filt[k * TJN + 0], fs1 = filt[k * TJN + 1];
  float fs2 = filt[k * TJN + 2], fs3 = filt[k * TJN + 3];
  const float* ur = U2 + (long)k * DD;
  const unsigned short* wr = Wft + (long)j * DD;
  float acc = 0.f;
#pragma unroll
  for (int t = 0; t < 4; t++){
    float a = 0.f;
    for (int c = t * 128; c < t * 128 + 128; c += 8){
      float4 x0 = *(const float4*)(ur + c);
      float4 x1 = *(const float4*)(ur + c + 4);
      ushort4 w0 = *(const ushort4*)(wr + c);
      ushort4 w1 = *(const ushort4*)(wr + c + 4);
      a += x0.x * bf2f(w0.x) + x0.y * bf2f(w0.y) + x0.z * bf2f(w0.z) + x0.w * bf2f(w0.w)
         + x1.x * bf2f(w1.x) + x1.y * bf2f(w1.y) + x1.z * bf2f(w1.z) + x1.w * bf2f(w1.w);
    }
    acc += (t == 0 ? fs0 : t == 1 ? fs1 : t == 2 ? fs2 : fs3) * a;
  }
  M2t[(long)j * KE + k] = f2bf(acc);
}

// ---------------- host orchestration ----------------
extern "C" void kernel_launch(void* const* d_in, const int* in_sizes, int n_in,
                              void* d_out, int out_size, void* d_ws, size_t ws_size,
                              hipStream_t stream){
  const int E = in_sizes[1] / 2;
  const long NB = (long)NN * DD;
  float* ws = (float*)d_ws;
  (void)n_in;

  size_t cur = 0;
  auto alloc = [&](size_t n){ size_t o = cur; cur += (n + 63) & ~(size_t)63; return o; };

  size_t o_flags = alloc(64);
  size_t o_zero  = cur;                      // ---- zeroed region ----
  size_t o_U     = alloc((size_t)KE * DD);
  size_t o_U2    = alloc((size_t)KE * DD);
  size_t o_stats = alloc(6 * DD);
  size_t o_evsum = alloc(KE);
  size_t o_ideg  = alloc(NN);
  size_t o_cur   = alloc(NN);
  size_t zlen    = cur - o_zero;             // -----------------------
  size_t o_dinv  = alloc(NN);
  size_t o_rowp  = alloc(NN + 64);
  size_t o_filt  = alloc(KE * TJN);          // contiguous param block start
  size_t o_bgcn  = alloc(DD);
  size_t o_b2    = alloc(DD);
  size_t o_bfus  = alloc(DD);
  size_t o_bff1  = alloc(2 * DD);
  size_t o_bff2  = alloc(DD);
  size_t o_bn    = alloc(6 * DD);            // contiguous param block end
  size_t o_Wgt   = alloc((size_t)DD * DD / 2);
  size_t o_W2t   = alloc((size_t)DD * DD / 2);
  size_t o_Wft   = alloc((size_t)DD * DD / 2);
  size_t o_W1t   = alloc((size_t)DD * DD);          // [1024][512] bf16
  size_t o_Wff2t = alloc((size_t)DD * DD);          // [512][1024] bf16
  size_t o_Ut    = alloc((size_t)KE * DD / 2);
  size_t o_M2t   = alloc((size_t)KE * DD / 2);      // [512][128] bf16
  size_t o_idx   = alloc((size_t)2 * E);
  size_t o_csr   = alloc((size_t)E);
  size_t o_part  = alloc((size_t)ZC * KE * DD);     // split-K partials (16.8 MB)
  size_t o_BF    = alloc(NB);                       // fp32 N x D (also hosts XbT/EVbT early)
  size_t o_BA    = alloc(NB / 2);                   // bf16 N x D (also hosts VAt)
  size_t o_BHL   = alloc(NB / 2);                   // bf16 N x D; BA+BHL = F1 [N,1024]
  size_t o_Xb    = alloc(NB / 2);                   // bf16 copy of x
  size_t o_EVb   = alloc((size_t)NN * KE / 2);      // bf16 copy of eigenvector
  size_t o_Hb    = alloc(NB / 2);                   // bf16 copy of h

  if (cur * 4 > ws_size){
    zero_out_bf16<<<2048, 256, 0, stream>>>(d_out, (long)out_size * 2);
    return;
  }

  int* flags = (int*)(ws + o_flags);
  float* BF  = ws + o_BF;
  void* BA   = (void*)(ws + o_BA);
  void* BHL  = (void*)(ws + o_BHL);
  void* F1   = BA;
  int* srcv  = (int*)(ws + o_idx);
  int* dstv  = srcv + E;
  int* ideg  = (int*)(ws + o_ideg);
  int* cursor= (int*)(ws + o_cur);
  int* rowp  = (int*)(ws + o_rowp);
  int* csr   = (int*)(ws + o_csr);
  float* dinv= ws + o_dinv;
  float* U   = ws + o_U;
  float* U2  = ws + o_U2;
  float* st  = ws + o_stats;
  float* Part= ws + o_part;
  unsigned short* Wgt   = (unsigned short*)(ws + o_Wgt);
  unsigned short* W2t   = (unsigned short*)(ws + o_W2t);
  unsigned short* Wft   = (unsigned short*)(ws + o_Wft);
  unsigned short* W1t   = (unsigned short*)(ws + o_W1t);
  unsigned short* Wff2t = (unsigned short*)(ws + o_Wff2t);
  unsigned short* Ut    = (unsigned short*)(ws + o_Ut);
  unsigned short* M2t   = (unsigned short*)(ws + o_M2t);
  unsigned short* Xb    = (unsigned short*)(ws + o_Xb);
  unsigned short* EVb   = (unsigned short*)(ws + o_EVb);
  unsigned short* Hb    = (unsigned short*)(ws + o_Hb);
  // transposed-K operands live in the BF region until the fusion GEMM needs BF:
  // XbT [512][KPAD] = 12,804,096 floats; EVbT [128][KPAD] starts at +12,804,160.
  unsigned short* XbT  = (unsigned short*)(ws + o_BF);
  unsigned short* EVbT = (unsigned short*)(ws + o_BF + 12804160);
  unsigned short* VAt  = (unsigned short*)BA;       // [512][KPAD] (tail spills into BHL; dead before BHL use)

  detect_kernel<<<1, 64, 0, stream>>>(d_in[0], d_in[1], flags);
  hipMemsetAsync(ws + o_zero, 0, zlen * 4, stream);

  P13 pp;
  pp.p[0] = d_in[3];  pp.p[1] = d_in[5];  pp.p[2] = d_in[7];  pp.p[3] = d_in[9];
  pp.p[4] = d_in[17]; pp.p[5] = d_in[19];
  for (int i = 0; i < 6; i++) pp.p[6 + i] = d_in[10 + i];
  cvt_params<<<26, 256, 0, stream>>>(pp, ws + o_filt, flags);

  // fused straight-bf16 + padded-transpose conversions
  cvt_bt<<<dim3(8, 782), 256, 0, stream>>>(d_in[0], Xb,  XbT,  NN, DD, KPAD, flags);
  cvt_bt<<<dim3(2, 782), 256, 0, stream>>>(d_in[2], EVb, EVbT, NN, KE, KPAD, flags);
  // weight transposes (coalesced both sides)
  cvt_t<<<dim3(8, 8),   256, 0, stream>>>(d_in[4],  Wgt,   DD, DD, DD, 0, 0, 2, flags);
  cvt_t<<<dim3(2, 8, 4),256, 0, stream>>>(d_in[6],  W2t,   DD, 128, DD,
                                          (long)DD * 128, (long)128 * DD, 2, flags);
  cvt_t<<<dim3(8, 8),   256, 0, stream>>>(d_in[8],  Wft,   DD, DD, DD, 0, 0, 2, flags);
  cvt_t<<<dim3(16, 8),  256, 0, stream>>>(d_in[16], W1t,   DD, 2 * DD, DD, 0, 0, 2, flags);
  cvt_t<<<dim3(8, 16),  256, 0, stream>>>(d_in[18], Wff2t, 2 * DD, DD, 2 * DD, 0, 0, 2, flags);
  cvt_idx<<<4096, 256, 0, stream>>>(d_in[1], srcv, 2L * E, flags);

  // CSR build
  deg_kernel<<<(E + 255) / 256, 256, 0, stream>>>(dstv, ideg, E);
  scan_kernel<<<1, 1024, 0, stream>>>(ideg, rowp, E);
  dinv_kernel<<<(NN + 255) / 256, 256, 0, stream>>>(ideg, dinv);
  scatter_kernel<<<(E + 255) / 256, 256, 0, stream>>>(srcv, dstv, rowp, cursor, csr, E);

  const int MT = (NN + 127) / 128;   // 391
  dim3 blk(256);
  const void* Xr = d_in[0];

  // ---- global WaveGC branch (first: BF region still holds XbT/EVbT) ----
  gemm_sk<<<dim3(4, 1, ZC), blk, 0, stream>>>(EVbT, XbT, Part, KPAD);               // proj1
  reduce_part<<<256, 256, 0, stream>>>(Part, U);                                    // XU fp32
  evsum_kernel<<<MT, 256, 0, stream>>>(EVb, ws + o_evsum);
  wave_mix<<<256, 256, 0, stream>>>(U, W2t, ws + o_evsum, ws + o_b2,
                                    ws + o_filt, Ut);                               // -> Ut bf16
  gemm_mfma_t<<<dim3(4, MT), blk, 0, stream>>>(EVb, Ut, VAt, NN, KE, KE, KPAD,
                                               nullptr, 1);                         // V^T bf16
  gemm_sk<<<dim3(4, 1, ZC), blk, 0, stream>>>(EVbT, VAt, Part, KPAD);               // proj2
  reduce_part<<<256, 256, 0, stream>>>(Part, U2);
  mix2<<<256, 256, 0, stream>>>(U2, Wft, ws + o_filt, M2t);                         // COMB folded
  gemm_mfma<<<dim3(4, MT), blk, 0, stream>>>(EVb, M2t, BF, NN, DD, KE, KE, DD,
                                             ws + o_bfus, Xr, 1, 2, 0, flags);      // relu+X fp32
  bn_stats<<<MT, 512, 0, stream>>>(BF, st + 2 * DD, st + 3 * DD);
  bn_apply<<<4096, 256, 0, stream>>>(BF, st + 2 * DD, st + 3 * DD,
                                     ws + o_bn + 2 * DD, ws + o_bn + 3 * DD,
                                     nullptr, 0, BHL, 1, nullptr, flags);           // h_attn bf16

  // ---- local GCN branch ----
  gemm_mfma<<<dim3(4, MT), blk, 0, stream>>>(Xb, Wgt, BA, NN, DD, DD, DD, DD,
                                             nullptr, nullptr, 0, 0, 1, flags);     // xw bf16
  gcn_gather<<<NN, 64, 0, stream>>>(rowp, csr, dinv, BA, Xr, ws + o_bgcn, BF, flags);
  bn_stats<<<MT, 512, 0, stream>>>(BF, st + 0, st + DD);
  bn_apply<<<4096, 256, 0, stream>>>(BF, st + 0, st + DD,
                                     ws + o_bn + 0 * DD, ws + o_bn + 1 * DD,
                                     BHL, 1, BF, 0, Hb, flags);                     // h fp32 + bf16

  // ---- FFN ----
  gemm_mfma<<<dim3(8, MT), blk, 0, stream>>>(Hb, W1t, F1, NN, 2 * DD, DD, DD, 2 * DD,
                                             ws + o_bff1, nullptr, 1, 0, 1, flags); // F1 bf16
  gemm_mfma<<<dim3(4, MT), blk, 0, stream>>>((const unsigned short*)F1, Wff2t, BF,
                                             NN, DD, 2 * DD, 2 * DD, DD,
                                             ws + o_bff2, BF, 0, 0, 0, flags);      // ff2 + h
  bn_stats<<<MT, 512, 0, stream>>>(BF, st + 4 * DD, st + 5 * DD);
  bn_apply<<<4096, 256, 0, stream>>>(BF, st + 4 * DD, st + 5 * DD,
                                     ws + o_bn + 4 * DD, ws + o_bn + 5 * DD,
                                     nullptr, 0, d_out, 2, nullptr, flags);         // -> out
}

// Round 8
// 1486.098 us; speedup vs baseline: 1.2300x; 1.1719x over previous
//
#include <hip/hip_runtime.h>
#include <hip/hip_bf16.h>

#define NN 50000
#define DD 512
#define KE 128
#define TJN 4
#define BNEPS 1e-5f
#define ZC 64       // split-K chunks
#define KPAD 50016  // NN padded to mult of 32 (zero-filled in transposed operands)
#define SKE 800     // K-elems per split-K chunk (25 steps of 32; 64*800 >= KPAD)

typedef __attribute__((ext_vector_type(8))) short short8;
typedef __attribute__((ext_vector_type(4))) float floatx4;

__device__ __forceinline__ float bf2f(unsigned short h){
  return __uint_as_float(((unsigned int)h) << 16);
}
__device__ __forceinline__ unsigned short f2bf(float f){
  unsigned int u = __float_as_uint(f);
  unsigned int r = (u + 0x7FFF + ((u >> 16) & 1)) >> 16;
  return (unsigned short)r;
}
__device__ __forceinline__ float load1(const void* p, long i, int bf){
  if (bf) return bf2f(((const unsigned short*)p)[i]);
  return ((const float*)p)[i];
}
__device__ __forceinline__ void store1(void* p, long i, int bf, float v){
  if (bf) ((unsigned short*)p)[i] = f2bf(v);
  else ((float*)p)[i] = v;
}

// async global->LDS 16B (dest = wave-uniform base + lane*16)
typedef __attribute__((address_space(3))) unsigned int lds_uint_t;
typedef __attribute__((address_space(1))) unsigned int gbl_uint_t;
__device__ __forceinline__ void gload16(const void* gp, void* lp){
  __builtin_amdgcn_global_load_lds((const gbl_uint_t*)gp, (lds_uint_t*)lp, 16, 0, 0);
}

// ---------------- dtype sniffing ----------------
__global__ void detect_kernel(const void* xraw, const void* eraw, int* flags){
  if (blockIdx.x == 0 && threadIdx.x == 0){
    const unsigned short* p = (const unsigned short*)xraw;
    int cnt = 0;
    for (int i = 0; i < 128; i++){
      int e = (p[i] >> 7) & 0xFF;
      if (e >= 110 && e <= 133) cnt++;
    }
    flags[0] = (cnt >= 96) ? 1 : 0;
    const unsigned int* q = (const unsigned int*)eraw;
    int z = 0;
    for (int i = 0; i < 64; i++) if (q[2*i+1] == 0u) z++;
    flags[1] = (z >= 48) ? 1 : 0;
  }
}

// all small parameter vectors in one launch; dst layout matches alloc order:
// [filt 512][bgcn 512][b2 512][bfus 512][bff1 1024][bff2 512][bn 6x512]
struct P13 { const void* p[12]; };
__global__ void cvt_params(P13 pp, float* __restrict__ dst, const int* __restrict__ flags){
  int bf = flags[0];
  int i = blockIdx.x * 256 + threadIdx.x;
  if (i >= 6656) return;
  const void* s; int off;
  if (i < 2048){ s = pp.p[i >> 9]; off = i & 511; }
  else if (i < 3072){ s = pp.p[4]; off = i - 2048; }
  else if (i < 3584){ s = pp.p[5]; off = i - 3072; }
  else { int j = (i - 3584) >> 9; s = pp.p[6 + j]; off = (i - 3584) & 511; }
  dst[i] = load1(s, off, bf);
}

// fused: read raw src[K][Nc] (dtype per flags), write straight bf16 dst1[K][Nc]
// AND transposed bf16 dst2[Nc][ldK] with zero-fill for cols in [K, ldK).
__global__ __launch_bounds__(256) void cvt_bt(
    const void* __restrict__ src, unsigned short* __restrict__ dst1,
    unsigned short* __restrict__ dst2, int K, int Nc, int ldK,
    const int* __restrict__ flags){
  int bf = flags[0];
  __shared__ unsigned short T[64][66];
  int bk = blockIdx.y * 64, bc = blockIdx.x * 64;
  int tid = threadIdx.x;
#pragma unroll
  for (int p = 0; p < 16; p++){
    int idx = p * 256 + tid;
    int r = idx >> 6, c = idx & 63;
    unsigned short h = 0;
    if (bk + r < K){
      h = f2bf(load1(src, (long)(bk + r) * Nc + bc + c, bf));
      dst1[(long)(bk + r) * Nc + bc + c] = h;
    }
    T[r][c] = h;
  }
  __syncthreads();
#pragma unroll
  for (int p = 0; p < 16; p++){
    int idx = p * 256 + tid;
    int r = idx >> 6, c = idx & 63;
    if (bk + c < ldK)
      dst2[(long)(bc + r) * ldK + bk + c] = T[c][r];
  }
}

// tiled transpose+cvt: dst[Nc][ldK] (bf16) = src[K][Nc]; zero-fills dst cols in [K, ldK).
__global__ __launch_bounds__(256) void cvt_t(
    const void* __restrict__ src, unsigned short* __restrict__ dst,
    int K, int Nc, int ldK, long srcz, long dstz, int smode,
    const int* __restrict__ flags){
  int bf = (smode == 2) ? flags[0] : smode;
  __shared__ unsigned short T[64][66];
  int bk = blockIdx.y * 64, bc = blockIdx.x * 64;
  long so = (long)blockIdx.z * srcz;
  long dof = (long)blockIdx.z * dstz;
  int tid = threadIdx.x;
#pragma unroll
  for (int p = 0; p < 16; p++){
    int idx = p * 256 + tid;
    int r = idx >> 6, c = idx & 63;
    float v = 0.f;
    if (bk + r < K) v = load1(src, so + (long)(bk + r) * Nc + bc + c, bf);
    T[r][c] = f2bf(v);
  }
  __syncthreads();
#pragma unroll
  for (int p = 0; p < 16; p++){
    int idx = p * 256 + tid;
    int r = idx >> 6, c = idx & 63;
    if (bk + c < ldK)
      dst[dof + (long)(bc + r) * ldK + bk + c] = T[c][r];
  }
}

__global__ void cvt_idx(const void* __restrict__ src, int* __restrict__ dst,
                        long n, const int* __restrict__ flags){
  int w64 = flags[1];
  long i = (long)blockIdx.x * blockDim.x + threadIdx.x;
  long stride = (long)gridDim.x * blockDim.x;
  for (; i < n; i += stride)
    dst[i] = w64 ? (int)((const long long*)src)[i] : ((const int*)src)[i];
}

// ---------------- CSR build ----------------
__global__ void deg_kernel(const int* __restrict__ dst, int* __restrict__ deg, int E){
  int i = blockIdx.x * blockDim.x + threadIdx.x;
  if (i < E) atomicAdd(&deg[dst[i]], 1);
}

__global__ __launch_bounds__(1024) void scan_kernel(const int* __restrict__ deg,
                                                    int* __restrict__ rowptr, int E){
  __shared__ int lds[1024];
  int t = threadIdx.x;
  const int CH = (NN + 1023) / 1024;   // 49
  int base = t * CH;
  int s = 0;
  for (int i = 0; i < CH; i++){
    int idx = base + i;
    if (idx < NN) s += deg[idx];
  }
  lds[t] = s;
  __syncthreads();
  for (int off = 1; off < 1024; off <<= 1){
    int v = (t >= off) ? lds[t - off] : 0;
    __syncthreads();
    lds[t] += v;
    __syncthreads();
  }
  int ex = (t == 0) ? 0 : lds[t - 1];
  for (int i = 0; i < CH; i++){
    int idx = base + i;
    if (idx < NN){ rowptr[idx] = ex; ex += deg[idx]; }
  }
  if (t == 1023) rowptr[NN] = ex;
}

__global__ void dinv_kernel(const int* __restrict__ deg, float* __restrict__ dinv){
  int i = blockIdx.x * blockDim.x + threadIdx.x;
  if (i < NN) dinv[i] = rsqrtf((float)deg[i] + 1.0f);
}

__global__ void scatter_kernel(const int* __restrict__ srcv, const int* __restrict__ dstv,
                               const int* __restrict__ rowptr, int* __restrict__ cursor,
                               int* __restrict__ csr, int E){
  int i = blockIdx.x * blockDim.x + threadIdx.x;
  if (i < E){
    int d = dstv[i];
    int pos = atomicAdd(&cursor[d], 1);
    csr[rowptr[d] + pos] = srcv[i];
  }
}

// ---------------- fused GCN gather (agg + self-loop + residual + bias) ----------------
__global__ __launch_bounds__(64) void gcn_gather(
    const int* __restrict__ rowptr, const int* __restrict__ csr,
    const float* __restrict__ dinv, const void* __restrict__ xw /*bf16*/,
    const void* __restrict__ X, const float* __restrict__ bias,
    float* __restrict__ out, const int* __restrict__ flags){
  int d = blockIdx.x;
  int lane = threadIdx.x;
  __shared__ int s_idx[64];
  __shared__ float s_dv[64];
  int start = rowptr[d], end = rowptr[d + 1];
  float dd = dinv[d];
  float acc[8];
#pragma unroll
  for (int k = 0; k < 8; k++) acc[k] = 0.f;
  const unsigned short* xwp = (const unsigned short*)xw;
  int c0 = lane * 8;
  for (int j0 = start; j0 < end; j0 += 64){
    int cnt = min(64, end - j0);
    __syncthreads();
    if (lane < cnt){
      int s = csr[j0 + lane];
      s_idx[lane] = s;
      s_dv[lane] = dinv[s];
    }
    __syncthreads();
    for (int t = 0; t < cnt; t++){
      int s = s_idx[t];
      float nm = dd * s_dv[t];
      union { float4 f; unsigned short u[8]; } r;
      r.f = *(const float4*)(xwp + (long)s * DD + c0);
#pragma unroll
      for (int k = 0; k < 8; k++) acc[k] += nm * bf2f(r.u[k]);
    }
  }
  int xf = flags[0];
  long base = (long)d * DD + c0;
  union { float4 f; unsigned short u[8]; } sf;
  sf.f = *(const float4*)(xwp + base);
  float d2 = dd * dd;
#pragma unroll
  for (int k = 0; k < 8; k++)
    out[base + k] = load1(X, base + k, xf) + acc[k] + d2 * bf2f(sf.u[k]) + bias[c0 + k];
}

// ---------------- batch norm ----------------
__global__ __launch_bounds__(512) void bn_stats(const void* __restrict__ T, int tmode,
                                                float* __restrict__ sum,
                                                float* __restrict__ sumsq){
  int c = threadIdx.x;
  long r0 = (long)blockIdx.x * 128;
  float s = 0.f, q = 0.f;
  for (int r = 0; r < 128; r++){
    long rr = r0 + r;
    if (rr < NN){
      float v = load1(T, rr * DD + c, tmode);
      s += v; q += v * v;
    }
  }
  atomicAdd(&sum[c], s);
  atomicAdd(&sumsq[c], q);
}

__global__ void bn_apply(const void* __restrict__ T, int tmode,
                         const float* __restrict__ sum, const float* __restrict__ sumsq,
                         const float* __restrict__ g, const float* __restrict__ b,
                         const void* __restrict__ addsrc, int addmode,
                         void* __restrict__ out, int outmode,
                         const int* __restrict__ flags){
  int am = (addmode == 2) ? flags[0] : addmode;
  int om = (outmode == 2) ? flags[0] : outmode;
  long i = (long)blockIdx.x * blockDim.x + threadIdx.x;
  long stride = (long)gridDim.x * blockDim.x;
  long n = (long)NN * DD;
  const float invN = 1.0f / (float)NN;
  for (; i < n; i += stride){
    int c = (int)(i & 511);
    float m = sum[c] * invN;
    float var = sumsq[c] * invN - m * m;
    float v = (load1(T, i, tmode) - m) * rsqrtf(var + BNEPS) * g[c] + b[c];
    if (addsrc) v += load1(addsrc, i, am);
    store1(out, i, om, v);
  }
}

__global__ void zero_out_bf16(void* out, long nbytes){
  long i = (long)blockIdx.x * blockDim.x + threadIdx.x;
  long stride = (long)gridDim.x * blockDim.x;
  long n = nbytes / 2;
  for (; i < n; i += stride) ((unsigned short*)out)[i] = 0;
}

// ---------------- MFMA bf16 GEMM: C = act(A@Bt^T + bias) (+ addsrc) ----------------
// BK=32, 16 KB staging LDS. Epilogue: LDS-staged coalesced (unioned with staging
// buffers: 8 passes x 16 rows, fp32 pitch 132 -> 2-way-free ds_writes, short8 stores).
__global__ __launch_bounds__(256) void gemm_mfma(
    const unsigned short* __restrict__ A, const unsigned short* __restrict__ Bt,
    void* __restrict__ C, int M, int N, int Kd, int lda, int ldc,
    const float* __restrict__ bias, const void* __restrict__ addsrc, int dorelu,
    int addmode, int cmode, const int* __restrict__ flags){
  int fl = flags[0];
  int adbf = (addmode == 2) ? fl : addmode;
  int cbf = (cmode == 2) ? fl : cmode;
  __shared__ unsigned short lds[8192];   // Asl[0:4096) Bsl[4096:8192); epilogue sc overlays
  unsigned short* Asl = lds;
  unsigned short* Bsl = lds + 4096;
  const int tid = threadIdx.x;

  int nx = gridDim.x;
  int nwg = nx * gridDim.y;
  int p = blockIdx.y * nx + blockIdx.x;
  int q8 = nwg >> 3, r8 = nwg & 7;
  int xcd = p & 7, off = p >> 3;
  int id = (xcd < r8 ? xcd * (q8 + 1) : r8 * (q8 + 1) + (xcd - r8) * q8) + off;
  int by = id / nx, bx = id - by * nx;
  const int bm = by * 128, bn = bx * 128;

  const int lane = tid & 63, wave = tid >> 6;
  const int wm = (wave & 1) * 64, wn = (wave >> 1) * 64;
  const int q = lane >> 4, l16 = lane & 15;
  const int swz = (q ^ ((l16 >> 1) & 3)) << 3;
  floatx4 acc[4][4];
#pragma unroll
  for (int i = 0; i < 4; i++)
#pragma unroll
    for (int j = 0; j < 4; j++)
#pragma unroll
      for (int r = 0; r < 4; r++) acc[i][j][r] = 0.f;

  const int sbase = wave << 7;

  for (int k0 = 0; k0 < Kd; k0 += 32){
    __syncthreads();
#pragma unroll
    for (int pp = 0; pp < 2; pp++){
      int slot = sbase + (pp << 6) + lane;
      int row = slot >> 2;
      int ssl = (slot & 3) ^ ((slot >> 3) & 3);
      int rA = bm + row; if (rA > M - 1) rA = M - 1;
      gload16(A + (long)rA * lda + k0 + (ssl << 3), &Asl[(sbase + (pp << 6)) << 3]);
      gload16(Bt + (long)(bn + row) * Kd + k0 + (ssl << 3), &Bsl[(sbase + (pp << 6)) << 3]);
    }
    __syncthreads();
    short8 af[4], bfr[4];
#pragma unroll
    for (int i = 0; i < 4; i++){
      int ra = wm + i * 16 + l16;
      af[i] = *(const short8*)&Asl[(ra << 5) + swz];
      int rb = wn + i * 16 + l16;
      bfr[i] = *(const short8*)&Bsl[(rb << 5) + swz];
    }
#pragma unroll
    for (int i = 0; i < 4; i++)
#pragma unroll
      for (int j = 0; j < 4; j++)
        acc[i][j] = __builtin_amdgcn_mfma_f32_16x16x32_bf16(af[i], bfr[j], acc[i][j], 0, 0, 0);
  }
  // ---- LDS-staged epilogue: 8 passes of 16 rows ----
  __syncthreads();
  float* sc = (float*)lds;   // 16 x 132 floats = 8448 B <= 16 KB
#pragma unroll
  for (int ps = 0; ps < 8; ps++){
    int i0 = ps & 3;
    int wmp = (ps >> 2) * 64;
    if (wm == wmp){
#pragma unroll
      for (int j = 0; j < 4; j++){
        int col = wn + j * 16 + l16;
        float bb = bias ? bias[bn + col] : 0.f;
#pragma unroll
        for (int r = 0; r < 4; r++){
          float v = acc[i0][j][r] + bb;
          if (dorelu) v = fmaxf(v, 0.f);
          sc[(q * 4 + r) * 132 + col] = v;
        }
      }
    }
    __syncthreads();
    {
      int rl = tid >> 4, c8 = (tid & 15) << 3;
      int grow = bm + ps * 16 + rl;
      if (grow < M){
        float4 f0 = *(float4*)&sc[rl * 132 + c8];
        float4 f1 = *(float4*)&sc[rl * 132 + c8 + 4];
        long offc = (long)grow * ldc + bn + c8;
        if (addsrc){
          if (adbf){
            ushort4 h0 = *(const ushort4*)((const unsigned short*)addsrc + offc);
            ushort4 h1 = *(const ushort4*)((const unsigned short*)addsrc + offc + 4);
            f0.x += bf2f(h0.x); f0.y += bf2f(h0.y); f0.z += bf2f(h0.z); f0.w += bf2f(h0.w);
            f1.x += bf2f(h1.x); f1.y += bf2f(h1.y); f1.z += bf2f(h1.z); f1.w += bf2f(h1.w);
          } else {
            float4 a0 = *(const float4*)((const float*)addsrc + offc);
            float4 a1 = *(const float4*)((const float*)addsrc + offc + 4);
            f0.x += a0.x; f0.y += a0.y; f0.z += a0.z; f0.w += a0.w;
            f1.x += a1.x; f1.y += a1.y; f1.z += a1.z; f1.w += a1.w;
          }
        }
        if (cbf){
          union { short8 s; unsigned short u[8]; } o;
          o.u[0] = f2bf(f0.x); o.u[1] = f2bf(f0.y); o.u[2] = f2bf(f0.z); o.u[3] = f2bf(f0.w);
          o.u[4] = f2bf(f1.x); o.u[5] = f2bf(f1.y); o.u[6] = f2bf(f1.z); o.u[7] = f2bf(f1.w);
          *(short8*)((unsigned short*)C + offc) = o.s;
        } else {
          *(float4*)((float*)C + offc) = f0;
          *(float4*)((float*)C + offc + 4) = f1;
        }
      }
    }
    __syncthreads();
  }
}

// ---- MFMA GEMM with TRANSPOSED bf16 output: Ct[col][row], ldct-strided ----
// BK=32, separate epilogue LDS (round-5 configuration).
__global__ __launch_bounds__(256) void gemm_mfma_t(
    const unsigned short* __restrict__ A, const unsigned short* __restrict__ Bt,
    unsigned short* __restrict__ Ct, int M, int Kd, int lda, int ldct,
    const float* __restrict__ bias, int dorelu){
  __shared__ unsigned short Asl[128 * 32];
  __shared__ unsigned short Bsl[128 * 32];
  __shared__ unsigned short sc[128 * 132];
  const int tid = threadIdx.x;

  int nx = gridDim.x;
  int nwg = nx * gridDim.y;
  int p = blockIdx.y * nx + blockIdx.x;
  int q8 = nwg >> 3, r8 = nwg & 7;
  int xcd = p & 7, off = p >> 3;
  int id = (xcd < r8 ? xcd * (q8 + 1) : r8 * (q8 + 1) + (xcd - r8) * q8) + off;
  int by = id / nx, bx = id - by * nx;
  const int bm = by * 128, bn = bx * 128;

  const int lane = tid & 63, wave = tid >> 6;
  const int wm = (wave & 1) * 64, wn = (wave >> 1) * 64;
  const int q = lane >> 4, l16 = lane & 15;
  const int swz = (q ^ ((l16 >> 1) & 3)) << 3;
  floatx4 acc[4][4];
#pragma unroll
  for (int i = 0; i < 4; i++)
#pragma unroll
    for (int j = 0; j < 4; j++)
#pragma unroll
      for (int r = 0; r < 4; r++) acc[i][j][r] = 0.f;

  const int sbase = wave << 7;

  for (int k0 = 0; k0 < Kd; k0 += 32){
    __syncthreads();
#pragma unroll
    for (int pp = 0; pp < 2; pp++){
      int slot = sbase + (pp << 6) + lane;
      int row = slot >> 2;
      int ssl = (slot & 3) ^ ((slot >> 3) & 3);
      int rA = bm + row; if (rA > M - 1) rA = M - 1;
      gload16(A + (long)rA * lda + k0 + (ssl << 3), &Asl[(sbase + (pp << 6)) << 3]);
      gload16(Bt + (long)(bn + row) * Kd + k0 + (ssl << 3), &Bsl[(sbase + (pp << 6)) << 3]);
    }
    __syncthreads();
    short8 af[4], bfr[4];
#pragma unroll
    for (int i = 0; i < 4; i++){
      int ra = wm + i * 16 + l16;
      af[i] = *(const short8*)&Asl[(ra << 5) + swz];
      int rb = wn + i * 16 + l16;
      bfr[i] = *(const short8*)&Bsl[(rb << 5) + swz];
    }
#pragma unroll
    for (int i = 0; i < 4; i++)
#pragma unroll
      for (int j = 0; j < 4; j++)
        acc[i][j] = __builtin_amdgcn_mfma_f32_16x16x32_bf16(af[i], bfr[j], acc[i][j], 0, 0, 0);
  }
  // stage C^T into LDS (pitch 132 keeps 8B alignment + conflict-free)
#pragma unroll
  for (int i = 0; i < 4; i++){
#pragma unroll
    for (int j = 0; j < 4; j++){
      int lr0 = wm + i * 16 + q * 4;
      int lc = wn + j * 16 + l16;
      float v0 = acc[i][j][0], v1 = acc[i][j][1], v2 = acc[i][j][2], v3 = acc[i][j][3];
      if (bias){ float bb = bias[bn + lc]; v0 += bb; v1 += bb; v2 += bb; v3 += bb; }
      if (dorelu){
        v0 = fmaxf(v0, 0.f); v1 = fmaxf(v1, 0.f);
        v2 = fmaxf(v2, 0.f); v3 = fmaxf(v3, 0.f);
      }
      ushort4 pk;
      pk.x = f2bf(v0); pk.y = f2bf(v1); pk.z = f2bf(v2); pk.w = f2bf(v3);
      *(ushort4*)&sc[lc * 132 + lr0] = pk;
    }
  }
  __syncthreads();
  // coalesced transposed store
#pragma unroll
  for (int pp = 0; pp < 8; pp++){
    int idx = pp * 2048 + tid * 8;
    int r2 = idx >> 7, c2 = idx & 127;
    int gc = bm + c2;
    if (gc >= ldct) continue;
    short8 o;
#pragma unroll
    for (int e = 0; e < 8; e++)
      ((unsigned short*)&o)[e] = (gc + e < M) ? sc[r2 * 132 + c2 + e] : (unsigned short)0;
    *(short8*)&Ct[(long)(bn + r2) * ldct + gc] = o;
  }
}

// ---- split-K MFMA NT: P[z][128][512] = A[128][KPAD] @ Bt[512][KPAD]^T partials ----
__global__ __launch_bounds__(256) void gemm_sk(
    const unsigned short* __restrict__ A, const unsigned short* __restrict__ Bt,
    float* __restrict__ P, int ldk){
  __shared__ unsigned short Asl[128 * 32];
  __shared__ unsigned short Bsl[128 * 32];
  const int tid = threadIdx.x;
  const int bn = blockIdx.x * 128;
  const int ks = blockIdx.z * SKE;
  const int ke = min(ks + SKE, KPAD);

  const int lane = tid & 63, wave = tid >> 6;
  const int wm = (wave & 1) * 64, wn = (wave >> 1) * 64;
  const int q = lane >> 4, l16 = lane & 15;
  const int swz = (q ^ ((l16 >> 1) & 3)) << 3;
  floatx4 acc[4][4];
#pragma unroll
  for (int i = 0; i < 4; i++)
#pragma unroll
    for (int j = 0; j < 4; j++)
#pragma unroll
      for (int r = 0; r < 4; r++) acc[i][j][r] = 0.f;

  const int sbase = wave << 7;

  for (int k0 = ks; k0 < ke; k0 += 32){
    __syncthreads();
#pragma unroll
    for (int pp = 0; pp < 2; pp++){
      int slot = sbase + (pp << 6) + lane;
      int row = slot >> 2;
      int ssl = (slot & 3) ^ ((slot >> 3) & 3);
      gload16(A + (long)row * ldk + k0 + (ssl << 3), &Asl[(sbase + (pp << 6)) << 3]);
      gload16(Bt + (long)(bn + row) * ldk + k0 + (ssl << 3), &Bsl[(sbase + (pp << 6)) << 3]);
    }
    __syncthreads();
    short8 af[4], bfr[4];
#pragma unroll
    for (int i = 0; i < 4; i++){
      int ra = wm + i * 16 + l16;
      af[i] = *(const short8*)&Asl[(ra << 5) + swz];
      int rb = wn + i * 16 + l16;
      bfr[i] = *(const short8*)&Bsl[(rb << 5) + swz];
    }
#pragma unroll
    for (int i = 0; i < 4; i++)
#pragma unroll
      for (int j = 0; j < 4; j++)
        acc[i][j] = __builtin_amdgcn_mfma_f32_16x16x32_bf16(af[i], bfr[j], acc[i][j], 0, 0, 0);
  }
  long base = (long)blockIdx.z * (KE * DD);
#pragma unroll
  for (int i = 0; i < 4; i++){
#pragma unroll
    for (int r = 0; r < 4; r++){
      int row = wm + i * 16 + q * 4 + r;
#pragma unroll
      for (int j = 0; j < 4; j++){
        int col = bn + wn + j * 16 + l16;
        P[base + (long)row * DD + col] = acc[i][j][r];
      }
    }
  }
}

__global__ void reduce_part(const float* __restrict__ P, float* __restrict__ C){
  int i = blockIdx.x * 256 + threadIdx.x;   // grid 256 -> 65536 elems
  float s = 0.f;
  for (int z = 0; z < ZC; z++) s += P[(long)z * (KE * DD) + i];
  C[i] = s;
}

// evsum[k] = sum_n EVb[n][k]
__global__ __launch_bounds__(256) void evsum_kernel(const unsigned short* __restrict__ EVb,
                                                    float* __restrict__ evsum){
  int b = blockIdx.x, t = threadIdx.x;
  int k = t & 127, half = t >> 7;
  float s = 0.f;
  for (int r = 0; r < 128; r += 2){
    int row = b * 128 + r + half;
    if (row < NN) s += bf2f(EVb[(long)row * KE + k]);
  }
  atomicAdd(&evsum[k], s);
}

// Ut[c][k] = filt(k, c>>7) * ( dot(XU[k,:], W2t[c,:]) + evsum[k]*b2[c] )
__global__ __launch_bounds__(256) void wave_mix(
    const float* __restrict__ XU, const unsigned short* __restrict__ W2t,
    const float* __restrict__ evsum, const float* __restrict__ b2,
    const float* __restrict__ filt, unsigned short* __restrict__ Ut){
  int i = blockIdx.x * 256 + threadIdx.x;   // grid 256 -> 65536
  int k = i >> 9, c = i & 511;
  float acc = evsum[k] * b2[c];
  const float* xr = XU + (long)k * DD;
  const unsigned short* wr = W2t + (long)c * DD;
#pragma unroll 4
  for (int d = 0; d < DD; d += 8){
    float4 x0 = *(const float4*)(xr + d);
    float4 x1 = *(const float4*)(xr + d + 4);
    ushort4 w0 = *(const ushort4*)(wr + d);
    ushort4 w1 = *(const ushort4*)(wr + d + 4);
    acc += x0.x * bf2f(w0.x) + x0.y * bf2f(w0.y) + x0.z * bf2f(w0.z) + x0.w * bf2f(w0.w)
         + x1.x * bf2f(w1.x) + x1.y * bf2f(w1.y) + x1.z * bf2f(w1.z) + x1.w * bf2f(w1.w);
  }
  float v = acc * filt[k * TJN + (c >> 7)];
  Ut[(long)c * KE + k] = f2bf(v);
}

// M2t[j][k] = sum_c (U2[k][c] * filt[k][c>>7]) * Wft[j][c]   (folds COMB into fusion)
__global__ __launch_bounds__(256) void mix2(
    const float* __restrict__ U2, const unsigned short* __restrict__ Wft,
    const float* __restrict__ filt, unsigned short* __restrict__ M2t){
  int i = blockIdx.x * 256 + threadIdx.x;   // grid 256 -> 65536
  int k = i & 127, j = i >> 7;
  float fs0 = filt[k * TJN + 0], fs1 = filt[k * TJN + 1];
  float fs2 = filt[k * TJN + 2], fs3 = filt[k * TJN + 3];
  const float* ur = U2 + (long)k * DD;
  const unsigned short* wr = Wft + (long)j * DD;
  float acc = 0.f;
#pragma unroll
  for (int t = 0; t < 4; t++){
    float a = 0.f;
    for (int c = t * 128; c < t * 128 + 128; c += 8){
      float4 x0 = *(const float4*)(ur + c);
      float4 x1 = *(const float4*)(ur + c + 4);
      ushort4 w0 = *(const ushort4*)(wr + c);
      ushort4 w1 = *(const ushort4*)(wr + c + 4);
      a += x0.x * bf2f(w0.x) + x0.y * bf2f(w0.y) + x0.z * bf2f(w0.z) + x0.w * bf2f(w0.w)
         + x1.x * bf2f(w1.x) + x1.y * bf2f(w1.y) + x1.z * bf2f(w1.z) + x1.w * bf2f(w1.w);
    }
    acc += (t == 0 ? fs0 : t == 1 ? fs1 : t == 2 ? fs2 : fs3) * a;
  }
  M2t[(long)j * KE + k] = f2bf(acc);
}

// ---------------- host orchestration ----------------
extern "C" void kernel_launch(void* const* d_in, const int* in_sizes, int n_in,
                              void* d_out, int out_size, void* d_ws, size_t ws_size,
                              hipStream_t stream){
  const int E = in_sizes[1] / 2;
  const long NB = (long)NN * DD;
  float* ws = (float*)d_ws;
  (void)n_in;

  size_t cur = 0;
  auto alloc = [&](size_t n){ size_t o = cur; cur += (n + 63) & ~(size_t)63; return o; };

  size_t o_flags = alloc(64);
  size_t o_zero  = cur;                      // ---- zeroed region ----
  size_t o_U     = alloc((size_t)KE * DD);
  size_t o_U2    = alloc((size_t)KE * DD);
  size_t o_stats = alloc(6 * DD);
  size_t o_evsum = alloc(KE);
  size_t o_ideg  = alloc(NN);
  size_t o_cur   = alloc(NN);
  size_t zlen    = cur - o_zero;             // -----------------------
  size_t o_dinv  = alloc(NN);
  size_t o_rowp  = alloc(NN + 64);
  size_t o_filt  = alloc(KE * TJN);          // contiguous param block start
  size_t o_bgcn  = alloc(DD);
  size_t o_b2    = alloc(DD);
  size_t o_bfus  = alloc(DD);
  size_t o_bff1  = alloc(2 * DD);
  size_t o_bff2  = alloc(DD);
  size_t o_bn    = alloc(6 * DD);            // contiguous param block end
  size_t o_Wgt   = alloc((size_t)DD * DD / 2);
  size_t o_W2t   = alloc((size_t)DD * DD / 2);
  size_t o_Wft   = alloc((size_t)DD * DD / 2);
  size_t o_W1t   = alloc((size_t)DD * DD);          // [1024][512] bf16
  size_t o_Wff2t = alloc((size_t)DD * DD);          // [512][1024] bf16
  size_t o_Ut    = alloc((size_t)KE * DD / 2);
  size_t o_M2t   = alloc((size_t)KE * DD / 2);      // [512][128] bf16
  size_t o_idx   = alloc((size_t)2 * E);
  size_t o_csr   = alloc((size_t)E);
  size_t o_part  = alloc((size_t)ZC * KE * DD);     // split-K partials (16.8 MB)
  size_t o_BF    = alloc(NB);                       // fp32 N x D (also hosts XbT/EVbT early)
  size_t o_BA    = alloc(NB / 2);                   // bf16 N x D (VAt / fusion-T / xw)
  size_t o_BHL   = alloc(NB / 2);                   // bf16 N x D (h_attn; F1 high half)
  size_t o_Xb    = alloc(NB / 2);                   // bf16 x copy; later FFN2-T
  size_t o_EVb   = alloc((size_t)NN * KE / 2);      // bf16 copy of eigenvector
  size_t o_Hb    = alloc(NB / 2);                   // bf16 h

  if (cur * 4 > ws_size){
    zero_out_bf16<<<2048, 256, 0, stream>>>(d_out, (long)out_size * 2);
    return;
  }

  int* flags = (int*)(ws + o_flags);
  float* BF  = ws + o_BF;
  void* BA   = (void*)(ws + o_BA);
  void* BHL  = (void*)(ws + o_BHL);
  void* F1   = BA;
  int* srcv  = (int*)(ws + o_idx);
  int* dstv  = srcv + E;
  int* ideg  = (int*)(ws + o_ideg);
  int* cursor= (int*)(ws + o_cur);
  int* rowp  = (int*)(ws + o_rowp);
  int* csr   = (int*)(ws + o_csr);
  float* dinv= ws + o_dinv;
  float* U   = ws + o_U;
  float* U2  = ws + o_U2;
  float* st  = ws + o_stats;
  float* Part= ws + o_part;
  unsigned short* Wgt   = (unsigned short*)(ws + o_Wgt);
  unsigned short* W2t   = (unsigned short*)(ws + o_W2t);
  unsigned short* Wft   = (unsigned short*)(ws + o_Wft);
  unsigned short* W1t   = (unsigned short*)(ws + o_W1t);
  unsigned short* Wff2t = (unsigned short*)(ws + o_Wff2t);
  unsigned short* Ut    = (unsigned short*)(ws + o_Ut);
  unsigned short* M2t   = (unsigned short*)(ws + o_M2t);
  unsigned short* Xb    = (unsigned short*)(ws + o_Xb);
  unsigned short* EVb   = (unsigned short*)(ws + o_EVb);
  unsigned short* Hb    = (unsigned short*)(ws + o_Hb);
  // transposed-K operands live in the BF region until gcn_gather needs BF:
  unsigned short* XbT  = (unsigned short*)(ws + o_BF);
  unsigned short* EVbT = (unsigned short*)(ws + o_BF + 12804160);
  unsigned short* VAt  = (unsigned short*)BA;   // [512][KPAD] (tail spills into BHL; dead before BHL use)

  detect_kernel<<<1, 64, 0, stream>>>(d_in[0], d_in[1], flags);
  hipMemsetAsync(ws + o_zero, 0, zlen * 4, stream);

  P13 pp;
  pp.p[0] = d_in[3];  pp.p[1] = d_in[5];  pp.p[2] = d_in[7];  pp.p[3] = d_in[9];
  pp.p[4] = d_in[17]; pp.p[5] = d_in[19];
  for (int i = 0; i < 6; i++) pp.p[6 + i] = d_in[10 + i];
  cvt_params<<<26, 256, 0, stream>>>(pp, ws + o_filt, flags);

  // fused straight-bf16 + padded-transpose conversions
  cvt_bt<<<dim3(8, 782), 256, 0, stream>>>(d_in[0], Xb,  XbT,  NN, DD, KPAD, flags);
  cvt_bt<<<dim3(2, 782), 256, 0, stream>>>(d_in[2], EVb, EVbT, NN, KE, KPAD, flags);
  // weight transposes (coalesced both sides)
  cvt_t<<<dim3(8, 8),   256, 0, stream>>>(d_in[4],  Wgt,   DD, DD, DD, 0, 0, 2, flags);
  cvt_t<<<dim3(2, 8, 4),256, 0, stream>>>(d_in[6],  W2t,   DD, 128, DD,
                                          (long)DD * 128, (long)128 * DD, 2, flags);
  cvt_t<<<dim3(8, 8),   256, 0, stream>>>(d_in[8],  Wft,   DD, DD, DD, 0, 0, 2, flags);
  cvt_t<<<dim3(16, 8),  256, 0, stream>>>(d_in[16], W1t,   DD, 2 * DD, DD, 0, 0, 2, flags);
  cvt_t<<<dim3(8, 16),  256, 0, stream>>>(d_in[18], Wff2t, 2 * DD, DD, 2 * DD, 0, 0, 2, flags);
  cvt_idx<<<4096, 256, 0, stream>>>(d_in[1], srcv, 2L * E, flags);

  // CSR build
  deg_kernel<<<(E + 255) / 256, 256, 0, stream>>>(dstv, ideg, E);
  scan_kernel<<<1, 1024, 0, stream>>>(ideg, rowp, E);
  dinv_kernel<<<(NN + 255) / 256, 256, 0, stream>>>(ideg, dinv);
  scatter_kernel<<<(E + 255) / 256, 256, 0, stream>>>(srcv, dstv, rowp, cursor, csr, E);

  const int MT = (NN + 127) / 128;   // 391
  dim3 blk(256);
  const void* Xr = d_in[0];

  // ---- global WaveGC branch (first: BF region still holds XbT/EVbT) ----
  gemm_sk<<<dim3(4, 1, ZC), blk, 0, stream>>>(EVbT, XbT, Part, KPAD);               // proj1
  reduce_part<<<256, 256, 0, stream>>>(Part, U);                                    // XU fp32
  evsum_kernel<<<MT, 256, 0, stream>>>(EVb, ws + o_evsum);
  wave_mix<<<256, 256, 0, stream>>>(U, W2t, ws + o_evsum, ws + o_b2,
                                    ws + o_filt, Ut);                               // -> Ut bf16
  gemm_mfma_t<<<dim3(4, MT), blk, 0, stream>>>(EVb, Ut, VAt, NN, KE, KE, KPAD,
                                               nullptr, 1);                         // V^T bf16
  gemm_sk<<<dim3(4, 1, ZC), blk, 0, stream>>>(EVbT, VAt, Part, KPAD);               // proj2
  reduce_part<<<256, 256, 0, stream>>>(Part, U2);
  mix2<<<256, 256, 0, stream>>>(U2, Wft, ws + o_filt, M2t);                         // COMB folded
  gemm_mfma<<<dim3(4, MT), blk, 0, stream>>>(EVb, M2t, BA, NN, DD, KE, KE, DD,
                                             ws + o_bfus, Xr, 1, 2, 1, flags);      // T2 bf16
  bn_stats<<<MT, 512, 0, stream>>>(BA, 1, st + 2 * DD, st + 3 * DD);
  bn_apply<<<4096, 256, 0, stream>>>(BA, 1, st + 2 * DD, st + 3 * DD,
                                     ws + o_bn + 2 * DD, ws + o_bn + 3 * DD,
                                     nullptr, 0, BHL, 1, flags);                    // h_attn bf16

  // ---- local GCN branch ----
  gemm_mfma<<<dim3(4, MT), blk, 0, stream>>>(Xb, Wgt, BA, NN, DD, DD, DD, DD,
                                             nullptr, nullptr, 0, 0, 1, flags);     // xw bf16
  gcn_gather<<<NN, 64, 0, stream>>>(rowp, csr, dinv, BA, Xr, ws + o_bgcn, BF, flags);
  bn_stats<<<MT, 512, 0, stream>>>(BF, 0, st + 0, st + DD);
  bn_apply<<<4096, 256, 0, stream>>>(BF, 0, st + 0, st + DD,
                                     ws + o_bn + 0 * DD, ws + o_bn + 1 * DD,
                                     BHL, 1, Hb, 1, flags);                         // h bf16 (Hb)

  // ---- FFN ----
  gemm_mfma<<<dim3(8, MT), blk, 0, stream>>>(Hb, W1t, F1, NN, 2 * DD, DD, DD, 2 * DD,
                                             ws + o_bff1, nullptr, 1, 0, 1, flags); // F1 bf16
  gemm_mfma<<<dim3(4, MT), blk, 0, stream>>>((const unsigned short*)F1, Wff2t, Xb,
                                             NN, DD, 2 * DD, 2 * DD, DD,
                                             ws + o_bff2, Hb, 0, 1, 1, flags);      // T3 bf16 (Xb)
  bn_stats<<<MT, 512, 0, stream>>>(Xb, 1, st + 4 * DD, st + 5 * DD);
  bn_apply<<<4096, 256, 0, stream>>>(Xb, 1, st + 4 * DD, st + 5 * DD,
                                     ws + o_bn + 4 * DD, ws + o_bn + 5 * DD,
                                     nullptr, 0, d_out, 2, flags);                  // -> out
}